// Round 2
// baseline (392.802 us; speedup 1.0000x reference)
//
#include <hip/hip_runtime.h>
#include <hip/hip_bf16.h>

// SynthesisConv: style affine -> demod -> conv_transpose(up=2,k=3) -> FIR 4x4
// -> noise + bias + lrelu*sqrt(2) + clamp(+-256).  Inputs f32, output f32.
//
//   style folds into x (B-operand column scale), dcoef folds into epilogue.
//   Z[(o,ky,kx),(b,i,j)] = sum_c w[o,c,ky,kx] * x'[b,c,i,j]   (one shared GEMM)
// R7: k_gemm LDS chunk-swizzle kills the 8-way ds_read_b128 bank conflict.
// R8: 256x256 tile, BK=32, 4-buffer LDS ring, counted vmcnt, setprio. (null:
//     MfmaUtil stayed 30% -> bottleneck is L3 staging reads, not schedule.)
// R9: XCD swizzle: each XCD owns an 8-wide x-slice (x=xcd*8+xoff, y=lin>>6)
//     so its 8 B-panels (2MB) stay L2-resident all kernel; A-panels (1MB)
//     shared by 8 concurrent blocks. Prefetch deepened to 3 tiles
//     (vmcnt 8/8/4/0 ladder). k_style: lane-cooperative float4 rows.

typedef unsigned short u16;
typedef unsigned int u32;
typedef u16 u16x8 __attribute__((ext_vector_type(8)));
typedef __bf16 bf16x8 __attribute__((ext_vector_type(8)));
typedef float f32x4 __attribute__((ext_vector_type(4)));

#define NB 16

__device__ __forceinline__ float bf2f(u16 v) {
  unsigned int u = ((unsigned int)v) << 16;
  float f;
  __builtin_memcpy(&f, &u, 4);
  return f;
}
__device__ __forceinline__ u16 f2bf(float f) {
  __hip_bfloat16 h = __float2bfloat16(f);  // RNE
  u16 r;
  __builtin_memcpy(&r, &h, 2);
  return r;
}
__device__ __forceinline__ void async16(u16* lds, const u16* g) {
  __builtin_amdgcn_global_load_lds(
      (const __attribute__((address_space(1))) u32*)g,
      (__attribute__((address_space(3))) u32*)lds, 16, 0, 0);
}

// ---- style[b,c] = sum_k wl[b,k]*aw[c,k]/sqrt(512) + ab[c] ---------------------
// R9: 64 c per block, 4 waves; each wave owns 16 rows sequentially. Lanes
// cooperate on one row: 2x float4 coalesced loads + shuffle reduce (old
// version had 64 lanes walking 64 different 2KB rows -> fully uncoalesced).
__global__ __launch_bounds__(256) void k_style(const float* __restrict__ wl,
                                               const float* __restrict__ aw,
                                               const float* __restrict__ ab,
                                               float* __restrict__ style) {
  __shared__ float lw[512];
  const int b = blockIdx.y;
  const int c0 = blockIdx.x << 6;
  const int t = threadIdx.x;
  for (int k = t; k < 512; k += 256) lw[k] = wl[b * 512 + k];
  __syncthreads();
  const int w = t >> 6, l = t & 63;
  const float4 lv0 = *(const float4*)(lw + (l << 2));
  const float4 lv1 = *(const float4*)(lw + 256 + (l << 2));
  for (int r = w; r < 64; r += 4) {
    const int c = c0 + r;
    const float* row = aw + (size_t)c * 512 + (l << 2);
    const float4 a0 = *(const float4*)(row);
    const float4 a1 = *(const float4*)(row + 256);
    float acc = lv0.x * a0.x + lv0.y * a0.y + lv0.z * a0.z + lv0.w * a0.w +
                lv1.x * a1.x + lv1.y * a1.y + lv1.z * a1.z + lv1.w * a1.w;
#pragma unroll
    for (int off = 32; off; off >>= 1) acc += __shfl_down(acc, off, 64);
    if (l == 0) style[b * 512 + c] = acc * 0.04419417382415922f + ab[c];
  }
}

// ---- merged: W2 pack (bf16, [o*9+kp][c]) + dcoef[b,o] ------------------------
__global__ __launch_bounds__(256) void k_wprep(const float* __restrict__ cw,
                                               const float* __restrict__ style,
                                               float* __restrict__ dcoef,
                                               u16* __restrict__ W2) {
  __shared__ u16 lw[4608];
  __shared__ float wsq[512];
  const int o = blockIdx.x, t = threadIdx.x;
  const float* src = cw + (size_t)o * 4608;
  for (int v = t; v < 4608; v += 256) {
    unsigned c = (unsigned)v / 9u;
    unsigned kp = (unsigned)v % 9u;
    lw[kp * 512 + c] = f2bf(src[v]);
  }
  for (int c = t; c < 512; c += 256) {
    const float* p = src + (size_t)c * 9;
    float s = 0.f;
#pragma unroll
    for (int k = 0; k < 9; ++k) {
      float v = p[k];
      s += v * v;
    }
    wsq[c] = s;
  }
  __syncthreads();
  u16* dst = W2 + (size_t)o * 4608;
  for (int v = t; v < 576; v += 256)
    *(u16x8*)(dst + v * 8) = *(const u16x8*)(lw + v * 8);
  const int w = t >> 6, l = t & 63;
  for (int b = w; b < NB; b += 4) {
    float part = 0.f;
#pragma unroll
    for (int c = l; c < 512; c += 64) {
      float st = style[b * 512 + c];
      part += st * st * wsq[c];
    }
#pragma unroll
    for (int off = 32; off; off >>= 1) part += __shfl_down(part, off, 64);
    if (l == 0) dcoef[b * 512 + o] = 1.0f / sqrtf(part + 1e-8f);
  }
}

// ---- xT[b,s,c] = bf16(x[b,c,s] * style[b,c])  (LDS 64x64 transpose) ----------
__global__ __launch_bounds__(256) void k_xt(const float* __restrict__ x,
                                            const float* __restrict__ style,
                                            u16* __restrict__ xT) {
  __shared__ u16 tile[64 * 66];
  const int b = blockIdx.z, c0 = blockIdx.y << 6, s0 = blockIdx.x << 6;
  const int t = threadIdx.x;
#pragma unroll
  for (int i = 0; i < 16; ++i) {
    int e = i * 256 + t;
    int cc = e >> 6, ss = e & 63;
    int c = c0 + cc;
    float v = x[(size_t)(b * 512 + c) * 1024 + s0 + ss] * style[b * 512 + c];
    tile[cc * 66 + ss] = f2bf(v);
  }
  __syncthreads();
#pragma unroll
  for (int e = 0; e < 2; ++e) {
    int idx = e * 256 + t;          // 512 = 64 rows x 8 col-groups
    int sc = idx >> 3;
    int cg = (idx & 7) << 3;
    u16x8 v;
#pragma unroll
    for (int g = 0; g < 8; ++g) v[g] = tile[(cg + g) * 66 + sc];
    *(u16x8*)(xT + (size_t)(b * 1024 + s0 + sc) * 512 + c0 + cg) = v;
  }
}

// ---- GEMM: Z[4608 x 16384] = W2[4608 x 512] * xT[16384 x 512]^T --------------
// 256x256 tile, BK=32, 8 waves (2M x 4N, each 128x64 of C), 16x16x32 bf16 MFMA.
// 4-buffer LDS ring, 3-K-tile-deep async prefetch, counted vmcnt(8) boundary
// waits (ladder 8/4/0 in epilogue), raw s_barrier, setprio around MFMA.
// XCD swizzle: lin=y*64+x -> XCD k=lin&7 owns x in [8k,8k+8) for all y, so
// its 8 B-panels (2 MB) stay L2-resident and 8 concurrent blocks share each
// A-panel. Chunk swizzle on stage-source + read side (R7) unchanged.
__global__ __launch_bounds__(512, 2) void k_gemm(const u16* __restrict__ W2,
                                                 const u16* __restrict__ xT,
                                                 u16* __restrict__ Z) {
  __shared__ u16 At[4][8192];  // [buf][256 rows x 32 k], 16 KiB each
  __shared__ u16 Bt[4][8192];
  const int t = threadIdx.x;
  // bijective XCD swizzle (grid 64 x 18)
  const int lin = blockIdx.y * 64 + blockIdx.x;
  const int xlog = ((lin & 7) << 3) | ((lin >> 3) & 7);
  const int ylog = lin >> 6;
  const int m0 = ylog << 8;
  const int n0 = xlog << 8;
  const int l = t & 63;
  const int w = t >> 6;        // wave 0..7
  const int wm = w >> 2;       // 0..1  (M half: 128 rows)
  const int wn = w & 3;        // 0..3  (N quarter: 64 cols)
  const int lrow = l & 15;
  const int lk = l >> 4;       // k-chunk 0..3

  // staging: thread covers LDS (row q*128 + (t>>2), slot t&3); the global
  // source chunk is pre-swizzled: (slot + (row>>1)) & 3 (q*128 is 0 mod 8).
  const int sr = t >> 2;
  const int sch = ((t & 3) + (sr >> 1)) & 3;
  const u16* gA = W2 + (size_t)(m0 + sr) * 512 + (sch << 3);
  const u16* gB = xT + (size_t)(n0 + sr) * 512 + (sch << 3);
  const int wb = w << 9;       // per-wave LDS base (u16): 64 lanes x 8 u16

  // read-side swizzled chunk offset: slot = (lk - (row>>1)) & 3; row>>1 mod 4
  // reduces to lrow>>1 for all fragment rows used below.
  const int sk8 = ((lk - (lrow >> 1)) & 3) << 3;
  const int arow = (wm << 7) + lrow;
  const int brow = (wn << 6) + lrow;

  f32x4 acc[8][4] = {};

#define STAGE_A(nb_, kt_)                                   \
  async16(&At[nb_][wb], gA + (kt_) * 32);                   \
  async16(&At[nb_][4096 + wb], gA + (kt_) * 32 + 65536)
#define STAGE_B(nb_, kt_)                                   \
  async16(&Bt[nb_][wb], gB + (kt_) * 32);                   \
  async16(&Bt[nb_][4096 + wb], gB + (kt_) * 32 + 65536)

  // prologue: tiles 0,1,2 in flight (12 loads); retire tile 0's 4 (counted).
  STAGE_A(0, 0);
  STAGE_B(0, 0);
  STAGE_A(1, 1);
  STAGE_B(1, 1);
  STAGE_A(2, 2);
  STAGE_B(2, 2);
  asm volatile("s_waitcnt vmcnt(8)" ::: "memory");
  asm volatile("s_barrier" ::: "memory");

  for (int kt = 0; kt < 16; ++kt) {
    const int buf = kt & 3;
    const int nb = (kt + 3) & 3;  // ring slot freed at end of tile kt-1
    const u16* Ab = At[buf];
    const u16* Bb = Bt[buf];
    bf16x8 av[4], bv[4], av2[4];

    // ---- phase 0: this wave's C rows 0-63 ----
#pragma unroll
    for (int i = 0; i < 4; ++i)
      av[i] = *(const bf16x8*)(Ab + (arow + i * 16) * 32 + sk8);
#pragma unroll
    for (int j = 0; j < 4; ++j)
      bv[j] = *(const bf16x8*)(Bb + (brow + j * 16) * 32 + sk8);
    if (kt < 13) { STAGE_A(nb, kt + 3); }
    asm volatile("s_barrier" ::: "memory");
    asm volatile("s_waitcnt lgkmcnt(0)" ::: "memory");
    __builtin_amdgcn_sched_barrier(0);
    __builtin_amdgcn_s_setprio(1);
#pragma unroll
    for (int i = 0; i < 4; ++i)
#pragma unroll
      for (int j = 0; j < 4; ++j)
        acc[i][j] = __builtin_amdgcn_mfma_f32_16x16x32_bf16(av[i], bv[j], acc[i][j], 0, 0, 0);
    __builtin_amdgcn_s_setprio(0);
    asm volatile("s_barrier" ::: "memory");

    // ---- phase 1: this wave's C rows 64-127 (bv reused from registers) ----
#pragma unroll
    for (int i = 0; i < 4; ++i)
      av2[i] = *(const bf16x8*)(Ab + (arow + 64 + i * 16) * 32 + sk8);
    if (kt < 13) { STAGE_B(nb, kt + 3); }
    asm volatile("s_barrier" ::: "memory");
    asm volatile("s_waitcnt lgkmcnt(0)" ::: "memory");
    __builtin_amdgcn_sched_barrier(0);
    __builtin_amdgcn_s_setprio(1);
#pragma unroll
    for (int i = 0; i < 4; ++i)
#pragma unroll
      for (int j = 0; j < 4; ++j)
        acc[i + 4][j] = __builtin_amdgcn_mfma_f32_16x16x32_bf16(av2[i], bv[j], acc[i + 4][j], 0, 0, 0);
    __builtin_amdgcn_s_setprio(0);

    // tile boundary: retire tile kt+1's 4 loads; keep kt+2/kt+3 in flight.
    if (kt <= 12) {
      asm volatile("s_waitcnt vmcnt(8)" ::: "memory");
      asm volatile("s_barrier" ::: "memory");
    } else if (kt == 13) {
      asm volatile("s_waitcnt vmcnt(4)" ::: "memory");
      asm volatile("s_barrier" ::: "memory");
    } else if (kt == 14) {
      asm volatile("s_waitcnt vmcnt(0)" ::: "memory");
      asm volatile("s_barrier" ::: "memory");
    }
  }
#undef STAGE_A
#undef STAGE_B

  const int mr = m0 + (wm << 7) + (lk << 2);
  const int nc = n0 + (wn << 6) + lrow;
#pragma unroll
  for (int i = 0; i < 8; ++i)
#pragma unroll
    for (int j = 0; j < 4; ++j)
#pragma unroll
      for (int r = 0; r < 4; ++r)
        Z[(size_t)(mr + i * 16 + r) * 16384 + nc + j * 16] = f2bf(acc[i][j][r]);
}

// ---- scatter: polyphase separable FIR + epilogue -----------------------------
__global__ __launch_bounds__(256) void k_scatter(
    const u16* __restrict__ Z, const float* __restrict__ dcoef,
    const float* __restrict__ noise, const float* __restrict__ nstr,
    const float* __restrict__ bias, float* __restrict__ out) {
  __shared__ u16 Zl[9 * 1024];
  __shared__ float Hl[3 * 2048];
  const int o = blockIdx.x;
  const int b = blockIdx.y;
  const int t = threadIdx.x;
  const u16* Zp = Z + (size_t)o * 9 * 16384 + (size_t)b * 1024;
  for (int v = t; v < 1152; v += 256) {
    int kp = v >> 7, off = (v & 127) << 3;
    *(u16x8*)(Zl + kp * 1024 + off) = *(const u16x8*)(Zp + (size_t)kp * 16384 + off);
  }
  __syncthreads();
#pragma unroll
  for (int e = 0; e < 12; ++e) {
    int idx = e * 256 + t;
    int ky = idx >> 10;
    int i = (idx >> 5) & 31;
    int j = idx & 31;
    const u16* P0 = Zl + (ky * 3 + 0) * 1024 + i * 32;
    const u16* P1 = P0 + 1024;
    const u16* P2 = P0 + 2048;
    float Ej = bf2f(P0[j]) + (j >= 1 ? bf2f(P2[j - 1]) : 0.f);
    float Ej1 = (j < 31 ? bf2f(P0[j + 1]) : 0.f) + bf2f(P2[j]);
    float Ojm = j >= 1 ? bf2f(P1[j - 1]) : 0.f;
    float Oj = bf2f(P1[j]);
    float Ojp = j < 31 ? bf2f(P1[j + 1]) : 0.f;
    float* hp = Hl + ky * 2048 + i * 64 + j;
    hp[0] = Ojm + 3.f * Ej + 3.f * Oj + Ej1;
    hp[32] = Ej + 3.f * Oj + 3.f * Ej1 + Ojp;
  }
  __syncthreads();
  const float dc = dcoef[b * 512 + o] * 0.0625f;
  const float ns = nstr[0];
  const float bo = bias[o];
  const int n = t & 63;
  const int i0 = (t >> 6) << 3;
  const int sw = ((n & 1) << 5) | (n >> 1);
  const float* H0 = Hl + sw;
  const float* H1 = Hl + 2048 + sw;
  const float* H2 = Hl + 4096 + sw;
  float h0 = H0[i0 * 64];
  float h1 = H1[i0 * 64];
  float h1p = (i0 > 0) ? H1[(i0 - 1) * 64] : 0.f;
  float h2p = (i0 > 0) ? H2[(i0 - 1) * 64] : 0.f;
  const float* nz = noise + ((size_t)b << 12) + n;
  float* op = out + (((size_t)(b * 512 + o)) << 12) + n;
#pragma unroll
  for (int s = 0; s < 8; ++s) {
    int i = i0 + s;
    float h0n = (i < 31) ? H0[(i + 1) * 64] : 0.f;
    float h1n = (i < 31) ? H1[(i + 1) * 64] : 0.f;
    float h2 = H2[i * 64];
    float ev = h1p + 3.f * (h0 + h2p) + 3.f * h1 + (h0n + h2);
    float od = (h0 + h2p) + 3.f * h1 + 3.f * (h0n + h2) + h1n;
    int m = 2 * i;
    float v0 = ev * dc + nz[(size_t)m * 64] * ns + bo;
    v0 = (v0 > 0.f ? v0 : 0.2f * v0) * 1.4142135623730951f;
    v0 = fminf(fmaxf(v0, -256.f), 256.f);
    op[(size_t)m * 64] = v0;
    float v1 = od * dc + nz[(size_t)(m + 1) * 64] * ns + bo;
    v1 = (v1 > 0.f ? v1 : 0.2f * v1) * 1.4142135623730951f;
    v1 = fminf(fmaxf(v1, -256.f), 256.f);
    op[(size_t)(m + 1) * 64] = v1;
    h0 = h0n;
    h1p = h1;
    h1 = h1n;
    h2p = h2;
  }
}

extern "C" void kernel_launch(void* const* d_in, const int* in_sizes, int n_in,
                              void* d_out, int out_size, void* d_ws, size_t ws_size,
                              hipStream_t stream) {
  const float* x = (const float*)d_in[0];
  const float* wl = (const float*)d_in[1];
  const float* aw = (const float*)d_in[2];
  const float* ab = (const float*)d_in[3];
  const float* cw = (const float*)d_in[4];
  const float* noise = (const float*)d_in[5];
  const float* nstr = (const float*)d_in[6];
  const float* bias = (const float*)d_in[7];
  float* out = (float*)d_out;

  float* style = (float*)d_ws;
  float* dcoef = style + 8192;
  u16* W2 = (u16*)(dcoef + 8192);
  u16* xT = W2 + 4608 * 512;
  u16* Z = xT + (size_t)16384 * 512;

  k_style<<<dim3(8, 16), 256, 0, stream>>>(wl, aw, ab, style);
  k_wprep<<<dim3(512), 256, 0, stream>>>(cw, style, dcoef, W2);
  k_xt<<<dim3(16, 8, 16), 256, 0, stream>>>(x, style, xT);
  k_gemm<<<dim3(64, 18), 512, 0, stream>>>(W2, xT, Z);
  k_scatter<<<dim3(512, 16), 256, 0, stream>>>(Z, dcoef, noise, nstr, bias, out);
}

// Round 3
// 379.321 us; speedup vs baseline: 1.0355x; 1.0355x over previous
//
#include <hip/hip_runtime.h>
#include <hip/hip_bf16.h>

// SynthesisConv: style affine -> demod -> conv_transpose(up=2,k=3) -> FIR 4x4
// -> noise + bias + lrelu*sqrt(2) + clamp(+-256).  Inputs f32, output f32.
//
//   style folds into x (B-operand column scale), dcoef folds into epilogue.
//   Z[(o,ky,kx),(b,i,j)] = sum_c w[o,c,ky,kx] * x'[b,c,i,j]   (one shared GEMM)
// R7: k_gemm LDS chunk-swizzle kills the 8-way ds_read_b128 bank conflict.
// R8: 256x256 tile, BK=32, 4-buffer LDS ring, counted vmcnt, setprio (null).
// R9: XCD swizzle (REGRESSED: WRITE 148->183MB amplification, FETCH flat ->
//     L2-residency theory refuted; R7-vs-R8 traffic halving w/ flat perf also
//     refutes L3-BW theory). k_style coalesced rewrite kept.
// R10: revert swizzle; barriers 5->1 per K-tile (ring slack makes mid-tile
//     barriers redundant: stage target (kt+3)&3==(kt-1)&3 whose readers all
//     passed the end-of-(kt-1) barrier); single lgkmcnt(0) + 32-MFMA cluster;
//     epilogue via LDS union [256][264] bf16 -> fully coalesced dwordx4 Z
//     stores (was 128 scattered 2B stores/thread).

typedef unsigned short u16;
typedef unsigned int u32;
typedef u16 u16x8 __attribute__((ext_vector_type(8)));
typedef __bf16 bf16x8 __attribute__((ext_vector_type(8)));
typedef float f32x4 __attribute__((ext_vector_type(4)));

#define NB 16

__device__ __forceinline__ float bf2f(u16 v) {
  unsigned int u = ((unsigned int)v) << 16;
  float f;
  __builtin_memcpy(&f, &u, 4);
  return f;
}
__device__ __forceinline__ u16 f2bf(float f) {
  __hip_bfloat16 h = __float2bfloat16(f);  // RNE
  u16 r;
  __builtin_memcpy(&r, &h, 2);
  return r;
}
__device__ __forceinline__ void async16(u16* lds, const u16* g) {
  __builtin_amdgcn_global_load_lds(
      (const __attribute__((address_space(1))) u32*)g,
      (__attribute__((address_space(3))) u32*)lds, 16, 0, 0);
}

// ---- style[b,c] = sum_k wl[b,k]*aw[c,k]/sqrt(512) + ab[c] ---------------------
__global__ __launch_bounds__(256) void k_style(const float* __restrict__ wl,
                                               const float* __restrict__ aw,
                                               const float* __restrict__ ab,
                                               float* __restrict__ style) {
  __shared__ float lw[512];
  const int b = blockIdx.y;
  const int c0 = blockIdx.x << 6;
  const int t = threadIdx.x;
  for (int k = t; k < 512; k += 256) lw[k] = wl[b * 512 + k];
  __syncthreads();
  const int w = t >> 6, l = t & 63;
  const float4 lv0 = *(const float4*)(lw + (l << 2));
  const float4 lv1 = *(const float4*)(lw + 256 + (l << 2));
  for (int r = w; r < 64; r += 4) {
    const int c = c0 + r;
    const float* row = aw + (size_t)c * 512 + (l << 2);
    const float4 a0 = *(const float4*)(row);
    const float4 a1 = *(const float4*)(row + 256);
    float acc = lv0.x * a0.x + lv0.y * a0.y + lv0.z * a0.z + lv0.w * a0.w +
                lv1.x * a1.x + lv1.y * a1.y + lv1.z * a1.z + lv1.w * a1.w;
#pragma unroll
    for (int off = 32; off; off >>= 1) acc += __shfl_down(acc, off, 64);
    if (l == 0) style[b * 512 + c] = acc * 0.04419417382415922f + ab[c];
  }
}

// ---- merged: W2 pack (bf16, [o*9+kp][c]) + dcoef[b,o] ------------------------
__global__ __launch_bounds__(256) void k_wprep(const float* __restrict__ cw,
                                               const float* __restrict__ style,
                                               float* __restrict__ dcoef,
                                               u16* __restrict__ W2) {
  __shared__ u16 lw[4608];
  __shared__ float wsq[512];
  const int o = blockIdx.x, t = threadIdx.x;
  const float* src = cw + (size_t)o * 4608;
  for (int v = t; v < 4608; v += 256) {
    unsigned c = (unsigned)v / 9u;
    unsigned kp = (unsigned)v % 9u;
    lw[kp * 512 + c] = f2bf(src[v]);
  }
  for (int c = t; c < 512; c += 256) {
    const float* p = src + (size_t)c * 9;
    float s = 0.f;
#pragma unroll
    for (int k = 0; k < 9; ++k) {
      float v = p[k];
      s += v * v;
    }
    wsq[c] = s;
  }
  __syncthreads();
  u16* dst = W2 + (size_t)o * 4608;
  for (int v = t; v < 576; v += 256)
    *(u16x8*)(dst + v * 8) = *(const u16x8*)(lw + v * 8);
  const int w = t >> 6, l = t & 63;
  for (int b = w; b < NB; b += 4) {
    float part = 0.f;
#pragma unroll
    for (int c = l; c < 512; c += 64) {
      float st = style[b * 512 + c];
      part += st * st * wsq[c];
    }
#pragma unroll
    for (int off = 32; off; off >>= 1) part += __shfl_down(part, off, 64);
    if (l == 0) dcoef[b * 512 + o] = 1.0f / sqrtf(part + 1e-8f);
  }
}

// ---- xT[b,s,c] = bf16(x[b,c,s] * style[b,c])  (LDS 64x64 transpose) ----------
__global__ __launch_bounds__(256) void k_xt(const float* __restrict__ x,
                                            const float* __restrict__ style,
                                            u16* __restrict__ xT) {
  __shared__ u16 tile[64 * 66];
  const int b = blockIdx.z, c0 = blockIdx.y << 6, s0 = blockIdx.x << 6;
  const int t = threadIdx.x;
#pragma unroll
  for (int i = 0; i < 16; ++i) {
    int e = i * 256 + t;
    int cc = e >> 6, ss = e & 63;
    int c = c0 + cc;
    float v = x[(size_t)(b * 512 + c) * 1024 + s0 + ss] * style[b * 512 + c];
    tile[cc * 66 + ss] = f2bf(v);
  }
  __syncthreads();
#pragma unroll
  for (int e = 0; e < 2; ++e) {
    int idx = e * 256 + t;          // 512 = 64 rows x 8 col-groups
    int sc = idx >> 3;
    int cg = (idx & 7) << 3;
    u16x8 v;
#pragma unroll
    for (int g = 0; g < 8; ++g) v[g] = tile[(cg + g) * 66 + sc];
    *(u16x8*)(xT + (size_t)(b * 1024 + s0 + sc) * 512 + c0 + cg) = v;
  }
}

// ---- GEMM: Z[4608 x 16384] = W2[4608 x 512] * xT[16384 x 512]^T --------------
// 256x256 tile, BK=32, 8 waves (2M x 4N, each 128x64 of C), 16x16x32 bf16 MFMA.
// 4-buffer LDS ring, 3-K-tile-deep async prefetch, ONE barrier per K-tile
// (vmcnt ladder 8/8/4/0), setprio around the 32-MFMA cluster. Epilogue: acc ->
// LDS [256][264] bf16 (ring reused via union; +8 u16 row pad keeps 16B align,
// lk-groups land on disjoint bank quads) -> coalesced 16B global stores.
__global__ __launch_bounds__(512, 2) void k_gemm(const u16* __restrict__ W2,
                                                 const u16* __restrict__ xT,
                                                 u16* __restrict__ Z) {
  __shared__ union SM {
    struct { u16 A[4][8192]; u16 B[4][8192]; } g;  // 128 KiB ring
    u16 C[256 * 264];                              // 132 KiB epilogue tile
  } sm;
  const int t = threadIdx.x;
  const int m0 = blockIdx.y << 8;
  const int n0 = blockIdx.x << 8;
  const int l = t & 63;
  const int w = t >> 6;        // wave 0..7
  const int wm = w >> 2;       // 0..1  (M half: 128 rows)
  const int wn = w & 3;        // 0..3  (N quarter: 64 cols)
  const int lrow = l & 15;
  const int lk = l >> 4;       // k-chunk 0..3

  // staging: thread covers LDS (row q*128 + (t>>2), slot t&3); the global
  // source chunk is pre-swizzled: (slot + (row>>1)) & 3 (q*128 is 0 mod 8).
  const int sr = t >> 2;
  const int sch = ((t & 3) + (sr >> 1)) & 3;
  const u16* gA = W2 + (size_t)(m0 + sr) * 512 + (sch << 3);
  const u16* gB = xT + (size_t)(n0 + sr) * 512 + (sch << 3);
  const int wb = w << 9;       // per-wave LDS base (u16): 64 lanes x 8 u16

  // read-side swizzled chunk offset (R7): per-lane constant.
  const int sk8 = ((lk - (lrow >> 1)) & 3) << 3;
  const int arow = (wm << 7) + lrow;
  const int brow = (wn << 6) + lrow;

  f32x4 acc[8][4] = {};

#define STAGE_A(nb_, kt_)                                   \
  async16(&sm.g.A[nb_][wb], gA + (kt_) * 32);               \
  async16(&sm.g.A[nb_][4096 + wb], gA + (kt_) * 32 + 65536)
#define STAGE_B(nb_, kt_)                                   \
  async16(&sm.g.B[nb_][wb], gB + (kt_) * 32);               \
  async16(&sm.g.B[nb_][4096 + wb], gB + (kt_) * 32 + 65536)

  // prologue: tiles 0,1,2 in flight (12 loads); retire tile 0's 4 (counted).
  STAGE_A(0, 0);
  STAGE_B(0, 0);
  STAGE_A(1, 1);
  STAGE_B(1, 1);
  STAGE_A(2, 2);
  STAGE_B(2, 2);
  asm volatile("s_waitcnt vmcnt(8)" ::: "memory");
  asm volatile("s_barrier" ::: "memory");

  for (int kt = 0; kt < 16; ++kt) {
    const int buf = kt & 3;
    const int nb = (kt + 3) & 3;  // slot whose readers finished at end of kt-1
    const u16* Ab = sm.g.A[buf];
    const u16* Bb = sm.g.B[buf];
    bf16x8 av[4], av2[4], bv[4];
#pragma unroll
    for (int i = 0; i < 4; ++i)
      av[i] = *(const bf16x8*)(Ab + (arow + i * 16) * 32 + sk8);
#pragma unroll
    for (int i = 0; i < 4; ++i)
      av2[i] = *(const bf16x8*)(Ab + (arow + 64 + i * 16) * 32 + sk8);
#pragma unroll
    for (int j = 0; j < 4; ++j)
      bv[j] = *(const bf16x8*)(Bb + (brow + j * 16) * 32 + sk8);
    if (kt < 13) {
      STAGE_A(nb, kt + 3);
      STAGE_B(nb, kt + 3);
    }
    asm volatile("s_waitcnt lgkmcnt(0)" ::: "memory");
    __builtin_amdgcn_sched_barrier(0);
    __builtin_amdgcn_s_setprio(1);
#pragma unroll
    for (int i = 0; i < 4; ++i)
#pragma unroll
      for (int j = 0; j < 4; ++j)
        acc[i][j] = __builtin_amdgcn_mfma_f32_16x16x32_bf16(av[i], bv[j], acc[i][j], 0, 0, 0);
#pragma unroll
    for (int i = 0; i < 4; ++i)
#pragma unroll
      for (int j = 0; j < 4; ++j)
        acc[i + 4][j] = __builtin_amdgcn_mfma_f32_16x16x32_bf16(av2[i], bv[j], acc[i + 4][j], 0, 0, 0);
    __builtin_amdgcn_s_setprio(0);
    // single per-tile boundary: retire next tile's 4 loads, sync all waves.
    if (kt <= 12) {
      asm volatile("s_waitcnt vmcnt(8)" ::: "memory");
      asm volatile("s_barrier" ::: "memory");
    } else if (kt == 13) {
      asm volatile("s_waitcnt vmcnt(4)" ::: "memory");
      asm volatile("s_barrier" ::: "memory");
    } else if (kt == 14) {
      asm volatile("s_waitcnt vmcnt(0)" ::: "memory");
      asm volatile("s_barrier" ::: "memory");
    }
  }
#undef STAGE_A
#undef STAGE_B

  __syncthreads();  // ring dead; reuse LDS as C tile
  // acc -> LDS bf16 [256][264]
  const int crow0 = (wm << 7) + (lk << 2);
  const int ccol0 = (wn << 6) + lrow;
#pragma unroll
  for (int i = 0; i < 8; ++i)
#pragma unroll
    for (int j = 0; j < 4; ++j)
#pragma unroll
      for (int r = 0; r < 4; ++r)
        sm.C[(crow0 + i * 16 + r) * 264 + ccol0 + j * 16] = f2bf(acc[i][j][r]);
  __syncthreads();
  // coalesced Z stores: 256 rows x 32 chunks of 16B; 16 chunks per thread.
  u16* zb = Z + (size_t)m0 * 16384 + n0;
#pragma unroll
  for (int k = 0; k < 16; ++k) {
    int c = (k << 9) | t;
    int row = c >> 5;
    int c8 = (c & 31) << 3;
    *(u16x8*)(zb + (size_t)row * 16384 + c8) = *(const u16x8*)(sm.C + row * 264 + c8);
  }
}

// ---- scatter: polyphase separable FIR + epilogue -----------------------------
__global__ __launch_bounds__(256) void k_scatter(
    const u16* __restrict__ Z, const float* __restrict__ dcoef,
    const float* __restrict__ noise, const float* __restrict__ nstr,
    const float* __restrict__ bias, float* __restrict__ out) {
  __shared__ u16 Zl[9 * 1024];
  __shared__ float Hl[3 * 2048];
  const int o = blockIdx.x;
  const int b = blockIdx.y;
  const int t = threadIdx.x;
  const u16* Zp = Z + (size_t)o * 9 * 16384 + (size_t)b * 1024;
  for (int v = t; v < 1152; v += 256) {
    int kp = v >> 7, off = (v & 127) << 3;
    *(u16x8*)(Zl + kp * 1024 + off) = *(const u16x8*)(Zp + (size_t)kp * 16384 + off);
  }
  __syncthreads();
#pragma unroll
  for (int e = 0; e < 12; ++e) {
    int idx = e * 256 + t;
    int ky = idx >> 10;
    int i = (idx >> 5) & 31;
    int j = idx & 31;
    const u16* P0 = Zl + (ky * 3 + 0) * 1024 + i * 32;
    const u16* P1 = P0 + 1024;
    const u16* P2 = P0 + 2048;
    float Ej = bf2f(P0[j]) + (j >= 1 ? bf2f(P2[j - 1]) : 0.f);
    float Ej1 = (j < 31 ? bf2f(P0[j + 1]) : 0.f) + bf2f(P2[j]);
    float Ojm = j >= 1 ? bf2f(P1[j - 1]) : 0.f;
    float Oj = bf2f(P1[j]);
    float Ojp = j < 31 ? bf2f(P1[j + 1]) : 0.f;
    float* hp = Hl + ky * 2048 + i * 64 + j;
    hp[0] = Ojm + 3.f * Ej + 3.f * Oj + Ej1;
    hp[32] = Ej + 3.f * Oj + 3.f * Ej1 + Ojp;
  }
  __syncthreads();
  const float dc = dcoef[b * 512 + o] * 0.0625f;
  const float ns = nstr[0];
  const float bo = bias[o];
  const int n = t & 63;
  const int i0 = (t >> 6) << 3;
  const int sw = ((n & 1) << 5) | (n >> 1);
  const float* H0 = Hl + sw;
  const float* H1 = Hl + 2048 + sw;
  const float* H2 = Hl + 4096 + sw;
  float h0 = H0[i0 * 64];
  float h1 = H1[i0 * 64];
  float h1p = (i0 > 0) ? H1[(i0 - 1) * 64] : 0.f;
  float h2p = (i0 > 0) ? H2[(i0 - 1) * 64] : 0.f;
  const float* nz = noise + ((size_t)b << 12) + n;
  float* op = out + (((size_t)(b * 512 + o)) << 12) + n;
#pragma unroll
  for (int s = 0; s < 8; ++s) {
    int i = i0 + s;
    float h0n = (i < 31) ? H0[(i + 1) * 64] : 0.f;
    float h1n = (i < 31) ? H1[(i + 1) * 64] : 0.f;
    float h2 = H2[i * 64];
    float ev = h1p + 3.f * (h0 + h2p) + 3.f * h1 + (h0n + h2);
    float od = (h0 + h2p) + 3.f * h1 + 3.f * (h0n + h2) + h1n;
    int m = 2 * i;
    float v0 = ev * dc + nz[(size_t)m * 64] * ns + bo;
    v0 = (v0 > 0.f ? v0 : 0.2f * v0) * 1.4142135623730951f;
    v0 = fminf(fmaxf(v0, -256.f), 256.f);
    op[(size_t)m * 64] = v0;
    float v1 = od * dc + nz[(size_t)(m + 1) * 64] * ns + bo;
    v1 = (v1 > 0.f ? v1 : 0.2f * v1) * 1.4142135623730951f;
    v1 = fminf(fmaxf(v1, -256.f), 256.f);
    op[(size_t)(m + 1) * 64] = v1;
    h0 = h0n;
    h1p = h1;
    h1 = h1n;
    h2p = h2;
  }
}

extern "C" void kernel_launch(void* const* d_in, const int* in_sizes, int n_in,
                              void* d_out, int out_size, void* d_ws, size_t ws_size,
                              hipStream_t stream) {
  const float* x = (const float*)d_in[0];
  const float* wl = (const float*)d_in[1];
  const float* aw = (const float*)d_in[2];
  const float* ab = (const float*)d_in[3];
  const float* cw = (const float*)d_in[4];
  const float* noise = (const float*)d_in[5];
  const float* nstr = (const float*)d_in[6];
  const float* bias = (const float*)d_in[7];
  float* out = (float*)d_out;

  float* style = (float*)d_ws;
  float* dcoef = style + 8192;
  u16* W2 = (u16*)(dcoef + 8192);
  u16* xT = W2 + 4608 * 512;
  u16* Z = xT + (size_t)16384 * 512;

  k_style<<<dim3(8, 16), 256, 0, stream>>>(wl, aw, ab, style);
  k_wprep<<<dim3(512), 256, 0, stream>>>(cw, style, dcoef, W2);
  k_xt<<<dim3(16, 8, 16), 256, 0, stream>>>(x, style, xT);
  k_gemm<<<dim3(64, 18), 512, 0, stream>>>(W2, xT, Z);
  k_scatter<<<dim3(512, 16), 256, 0, stream>>>(Z, dcoef, noise, nstr, bias, out);
}

// Round 4
// 354.084 us; speedup vs baseline: 1.1093x; 1.0713x over previous
//
#include <hip/hip_runtime.h>
#include <hip/hip_bf16.h>

// SynthesisConv: style affine -> demod -> conv_transpose(up=2,k=3) -> FIR 4x4
// -> noise + bias + lrelu*sqrt(2) + clamp(+-256).  Inputs f32, output f32.
//
//   style folds into x (B-operand column scale), dcoef folds into epilogue.
//   Z[(o,ky,kx),(b,i,j)] = sum_c w[o,c,ky,kx] * x'[b,c,i,j]   (one shared GEMM)
// R7: k_gemm LDS chunk-swizzle kills the 8-way ds_read_b128 bank conflict.
// R8: 256x256 tile, BK=32, 4-buffer LDS ring, counted vmcnt, setprio (null).
// R9: XCD swizzle (REGRESSED); k_style coalesced rewrite kept.
// R10: barriers 5->1 per K-tile + LDS-staged coalesced C-write. WORKED:
//      k_gemm fell out of top-5 (<111us). k_scatter now hottest (111us,
//      occupancy 31%, all pipes <40% -> latency-bound; LDS 42KB caps 3
//      blocks/CU; 256 thr = 12 waves/CU).
// R11: k_scatter -> 512 threads/block, same per-block work+LDS: 3 blocks/CU
//      x 8 waves = 24 waves/CU (2x latency hiding). Lane maps (n=t&63)
//      unchanged -> bank layout/coalescing identical.

typedef unsigned short u16;
typedef unsigned int u32;
typedef u16 u16x8 __attribute__((ext_vector_type(8)));
typedef __bf16 bf16x8 __attribute__((ext_vector_type(8)));
typedef float f32x4 __attribute__((ext_vector_type(4)));

#define NB 16

__device__ __forceinline__ float bf2f(u16 v) {
  unsigned int u = ((unsigned int)v) << 16;
  float f;
  __builtin_memcpy(&f, &u, 4);
  return f;
}
__device__ __forceinline__ u16 f2bf(float f) {
  __hip_bfloat16 h = __float2bfloat16(f);  // RNE
  u16 r;
  __builtin_memcpy(&r, &h, 2);
  return r;
}
__device__ __forceinline__ void async16(u16* lds, const u16* g) {
  __builtin_amdgcn_global_load_lds(
      (const __attribute__((address_space(1))) u32*)g,
      (__attribute__((address_space(3))) u32*)lds, 16, 0, 0);
}

// ---- style[b,c] = sum_k wl[b,k]*aw[c,k]/sqrt(512) + ab[c] ---------------------
__global__ __launch_bounds__(256) void k_style(const float* __restrict__ wl,
                                               const float* __restrict__ aw,
                                               const float* __restrict__ ab,
                                               float* __restrict__ style) {
  __shared__ float lw[512];
  const int b = blockIdx.y;
  const int c0 = blockIdx.x << 6;
  const int t = threadIdx.x;
  for (int k = t; k < 512; k += 256) lw[k] = wl[b * 512 + k];
  __syncthreads();
  const int w = t >> 6, l = t & 63;
  const float4 lv0 = *(const float4*)(lw + (l << 2));
  const float4 lv1 = *(const float4*)(lw + 256 + (l << 2));
  for (int r = w; r < 64; r += 4) {
    const int c = c0 + r;
    const float* row = aw + (size_t)c * 512 + (l << 2);
    const float4 a0 = *(const float4*)(row);
    const float4 a1 = *(const float4*)(row + 256);
    float acc = lv0.x * a0.x + lv0.y * a0.y + lv0.z * a0.z + lv0.w * a0.w +
                lv1.x * a1.x + lv1.y * a1.y + lv1.z * a1.z + lv1.w * a1.w;
#pragma unroll
    for (int off = 32; off; off >>= 1) acc += __shfl_down(acc, off, 64);
    if (l == 0) style[b * 512 + c] = acc * 0.04419417382415922f + ab[c];
  }
}

// ---- merged: W2 pack (bf16, [o*9+kp][c]) + dcoef[b,o] ------------------------
__global__ __launch_bounds__(256) void k_wprep(const float* __restrict__ cw,
                                               const float* __restrict__ style,
                                               float* __restrict__ dcoef,
                                               u16* __restrict__ W2) {
  __shared__ u16 lw[4608];
  __shared__ float wsq[512];
  const int o = blockIdx.x, t = threadIdx.x;
  const float* src = cw + (size_t)o * 4608;
  for (int v = t; v < 4608; v += 256) {
    unsigned c = (unsigned)v / 9u;
    unsigned kp = (unsigned)v % 9u;
    lw[kp * 512 + c] = f2bf(src[v]);
  }
  for (int c = t; c < 512; c += 256) {
    const float* p = src + (size_t)c * 9;
    float s = 0.f;
#pragma unroll
    for (int k = 0; k < 9; ++k) {
      float v = p[k];
      s += v * v;
    }
    wsq[c] = s;
  }
  __syncthreads();
  u16* dst = W2 + (size_t)o * 4608;
  for (int v = t; v < 576; v += 256)
    *(u16x8*)(dst + v * 8) = *(const u16x8*)(lw + v * 8);
  const int w = t >> 6, l = t & 63;
  for (int b = w; b < NB; b += 4) {
    float part = 0.f;
#pragma unroll
    for (int c = l; c < 512; c += 64) {
      float st = style[b * 512 + c];
      part += st * st * wsq[c];
    }
#pragma unroll
    for (int off = 32; off; off >>= 1) part += __shfl_down(part, off, 64);
    if (l == 0) dcoef[b * 512 + o] = 1.0f / sqrtf(part + 1e-8f);
  }
}

// ---- xT[b,s,c] = bf16(x[b,c,s] * style[b,c])  (LDS 64x64 transpose) ----------
__global__ __launch_bounds__(256) void k_xt(const float* __restrict__ x,
                                            const float* __restrict__ style,
                                            u16* __restrict__ xT) {
  __shared__ u16 tile[64 * 66];
  const int b = blockIdx.z, c0 = blockIdx.y << 6, s0 = blockIdx.x << 6;
  const int t = threadIdx.x;
#pragma unroll
  for (int i = 0; i < 16; ++i) {
    int e = i * 256 + t;
    int cc = e >> 6, ss = e & 63;
    int c = c0 + cc;
    float v = x[(size_t)(b * 512 + c) * 1024 + s0 + ss] * style[b * 512 + c];
    tile[cc * 66 + ss] = f2bf(v);
  }
  __syncthreads();
#pragma unroll
  for (int e = 0; e < 2; ++e) {
    int idx = e * 256 + t;          // 512 = 64 rows x 8 col-groups
    int sc = idx >> 3;
    int cg = (idx & 7) << 3;
    u16x8 v;
#pragma unroll
    for (int g = 0; g < 8; ++g) v[g] = tile[(cg + g) * 66 + sc];
    *(u16x8*)(xT + (size_t)(b * 1024 + s0 + sc) * 512 + c0 + cg) = v;
  }
}

// ---- GEMM: Z[4608 x 16384] = W2[4608 x 512] * xT[16384 x 512]^T --------------
// 256x256 tile, BK=32, 8 waves (2M x 4N, each 128x64 of C), 16x16x32 bf16 MFMA.
// 4-buffer LDS ring, 3-K-tile-deep async prefetch, ONE barrier per K-tile
// (vmcnt ladder 8/8/4/0), setprio around the 32-MFMA cluster. Epilogue: acc ->
// LDS [256][264] bf16 -> coalesced 16B global stores.
__global__ __launch_bounds__(512, 2) void k_gemm(const u16* __restrict__ W2,
                                                 const u16* __restrict__ xT,
                                                 u16* __restrict__ Z) {
  __shared__ union SM {
    struct { u16 A[4][8192]; u16 B[4][8192]; } g;  // 128 KiB ring
    u16 C[256 * 264];                              // 132 KiB epilogue tile
  } sm;
  const int t = threadIdx.x;
  const int m0 = blockIdx.y << 8;
  const int n0 = blockIdx.x << 8;
  const int l = t & 63;
  const int w = t >> 6;        // wave 0..7
  const int wm = w >> 2;       // 0..1  (M half: 128 rows)
  const int wn = w & 3;        // 0..3  (N quarter: 64 cols)
  const int lrow = l & 15;
  const int lk = l >> 4;       // k-chunk 0..3

  const int sr = t >> 2;
  const int sch = ((t & 3) + (sr >> 1)) & 3;
  const u16* gA = W2 + (size_t)(m0 + sr) * 512 + (sch << 3);
  const u16* gB = xT + (size_t)(n0 + sr) * 512 + (sch << 3);
  const int wb = w << 9;       // per-wave LDS base (u16): 64 lanes x 8 u16

  const int sk8 = ((lk - (lrow >> 1)) & 3) << 3;
  const int arow = (wm << 7) + lrow;
  const int brow = (wn << 6) + lrow;

  f32x4 acc[8][4] = {};

#define STAGE_A(nb_, kt_)                                   \
  async16(&sm.g.A[nb_][wb], gA + (kt_) * 32);               \
  async16(&sm.g.A[nb_][4096 + wb], gA + (kt_) * 32 + 65536)
#define STAGE_B(nb_, kt_)                                   \
  async16(&sm.g.B[nb_][wb], gB + (kt_) * 32);               \
  async16(&sm.g.B[nb_][4096 + wb], gB + (kt_) * 32 + 65536)

  STAGE_A(0, 0);
  STAGE_B(0, 0);
  STAGE_A(1, 1);
  STAGE_B(1, 1);
  STAGE_A(2, 2);
  STAGE_B(2, 2);
  asm volatile("s_waitcnt vmcnt(8)" ::: "memory");
  asm volatile("s_barrier" ::: "memory");

  for (int kt = 0; kt < 16; ++kt) {
    const int buf = kt & 3;
    const int nb = (kt + 3) & 3;  // slot whose readers finished at end of kt-1
    const u16* Ab = sm.g.A[buf];
    const u16* Bb = sm.g.B[buf];
    bf16x8 av[4], av2[4], bv[4];
#pragma unroll
    for (int i = 0; i < 4; ++i)
      av[i] = *(const bf16x8*)(Ab + (arow + i * 16) * 32 + sk8);
#pragma unroll
    for (int i = 0; i < 4; ++i)
      av2[i] = *(const bf16x8*)(Ab + (arow + 64 + i * 16) * 32 + sk8);
#pragma unroll
    for (int j = 0; j < 4; ++j)
      bv[j] = *(const bf16x8*)(Bb + (brow + j * 16) * 32 + sk8);
    if (kt < 13) {
      STAGE_A(nb, kt + 3);
      STAGE_B(nb, kt + 3);
    }
    asm volatile("s_waitcnt lgkmcnt(0)" ::: "memory");
    __builtin_amdgcn_sched_barrier(0);
    __builtin_amdgcn_s_setprio(1);
#pragma unroll
    for (int i = 0; i < 4; ++i)
#pragma unroll
      for (int j = 0; j < 4; ++j)
        acc[i][j] = __builtin_amdgcn_mfma_f32_16x16x32_bf16(av[i], bv[j], acc[i][j], 0, 0, 0);
#pragma unroll
    for (int i = 0; i < 4; ++i)
#pragma unroll
      for (int j = 0; j < 4; ++j)
        acc[i + 4][j] = __builtin_amdgcn_mfma_f32_16x16x32_bf16(av2[i], bv[j], acc[i + 4][j], 0, 0, 0);
    __builtin_amdgcn_s_setprio(0);
    if (kt <= 12) {
      asm volatile("s_waitcnt vmcnt(8)" ::: "memory");
      asm volatile("s_barrier" ::: "memory");
    } else if (kt == 13) {
      asm volatile("s_waitcnt vmcnt(4)" ::: "memory");
      asm volatile("s_barrier" ::: "memory");
    } else if (kt == 14) {
      asm volatile("s_waitcnt vmcnt(0)" ::: "memory");
      asm volatile("s_barrier" ::: "memory");
    }
  }
#undef STAGE_A
#undef STAGE_B

  __syncthreads();  // ring dead; reuse LDS as C tile
  const int crow0 = (wm << 7) + (lk << 2);
  const int ccol0 = (wn << 6) + lrow;
#pragma unroll
  for (int i = 0; i < 8; ++i)
#pragma unroll
    for (int j = 0; j < 4; ++j)
#pragma unroll
      for (int r = 0; r < 4; ++r)
        sm.C[(crow0 + i * 16 + r) * 264 + ccol0 + j * 16] = f2bf(acc[i][j][r]);
  __syncthreads();
  u16* zb = Z + (size_t)m0 * 16384 + n0;
#pragma unroll
  for (int k = 0; k < 16; ++k) {
    int c = (k << 9) | t;
    int row = c >> 5;
    int c8 = (c & 31) << 3;
    *(u16x8*)(zb + (size_t)row * 16384 + c8) = *(const u16x8*)(sm.C + row * 264 + c8);
  }
}

// ---- scatter: polyphase separable FIR + epilogue -----------------------------
// R11: 512 threads, same 42KB LDS -> 24 waves/CU. Lane math (n=t&63) kept.
__global__ __launch_bounds__(512) void k_scatter(
    const u16* __restrict__ Z, const float* __restrict__ dcoef,
    const float* __restrict__ noise, const float* __restrict__ nstr,
    const float* __restrict__ bias, float* __restrict__ out) {
  __shared__ u16 Zl[9 * 1024];
  __shared__ float Hl[3 * 2048];
  const int o = blockIdx.x;
  const int b = blockIdx.y;
  const int t = threadIdx.x;
  const u16* Zp = Z + (size_t)o * 9 * 16384 + (size_t)b * 1024;
  for (int v = t; v < 1152; v += 512) {
    int kp = v >> 7, off = (v & 127) << 3;
    *(u16x8*)(Zl + kp * 1024 + off) = *(const u16x8*)(Zp + (size_t)kp * 16384 + off);
  }
  __syncthreads();
#pragma unroll
  for (int e = 0; e < 6; ++e) {
    int idx = e * 512 + t;
    int ky = idx >> 10;
    int i = (idx >> 5) & 31;
    int j = idx & 31;
    const u16* P0 = Zl + (ky * 3 + 0) * 1024 + i * 32;
    const u16* P1 = P0 + 1024;
    const u16* P2 = P0 + 2048;
    float Ej = bf2f(P0[j]) + (j >= 1 ? bf2f(P2[j - 1]) : 0.f);
    float Ej1 = (j < 31 ? bf2f(P0[j + 1]) : 0.f) + bf2f(P2[j]);
    float Ojm = j >= 1 ? bf2f(P1[j - 1]) : 0.f;
    float Oj = bf2f(P1[j]);
    float Ojp = j < 31 ? bf2f(P1[j + 1]) : 0.f;
    float* hp = Hl + ky * 2048 + i * 64 + j;
    hp[0] = Ojm + 3.f * Ej + 3.f * Oj + Ej1;
    hp[32] = Ej + 3.f * Oj + 3.f * Ej1 + Ojp;
  }
  __syncthreads();
  const float dc = dcoef[b * 512 + o] * 0.0625f;
  const float ns = nstr[0];
  const float bo = bias[o];
  const int n = t & 63;
  const int i0 = (t >> 6) << 2;   // 8 groups x 4 rows
  const int sw = ((n & 1) << 5) | (n >> 1);
  const float* H0 = Hl + sw;
  const float* H1 = Hl + 2048 + sw;
  const float* H2 = Hl + 4096 + sw;
  float h0 = H0[i0 * 64];
  float h1 = H1[i0 * 64];
  float h1p = (i0 > 0) ? H1[(i0 - 1) * 64] : 0.f;
  float h2p = (i0 > 0) ? H2[(i0 - 1) * 64] : 0.f;
  const float* nz = noise + ((size_t)b << 12) + n;
  float* op = out + (((size_t)(b * 512 + o)) << 12) + n;
#pragma unroll
  for (int s = 0; s < 4; ++s) {
    int i = i0 + s;
    float h0n = (i < 31) ? H0[(i + 1) * 64] : 0.f;
    float h1n = (i < 31) ? H1[(i + 1) * 64] : 0.f;
    float h2 = H2[i * 64];
    float ev = h1p + 3.f * (h0 + h2p) + 3.f * h1 + (h0n + h2);
    float od = (h0 + h2p) + 3.f * h1 + 3.f * (h0n + h2) + h1n;
    int m = 2 * i;
    float v0 = ev * dc + nz[(size_t)m * 64] * ns + bo;
    v0 = (v0 > 0.f ? v0 : 0.2f * v0) * 1.4142135623730951f;
    v0 = fminf(fmaxf(v0, -256.f), 256.f);
    op[(size_t)m * 64] = v0;
    float v1 = od * dc + nz[(size_t)(m + 1) * 64] * ns + bo;
    v1 = (v1 > 0.f ? v1 : 0.2f * v1) * 1.4142135623730951f;
    v1 = fminf(fmaxf(v1, -256.f), 256.f);
    op[(size_t)(m + 1) * 64] = v1;
    h0 = h0n;
    h1p = h1;
    h1 = h1n;
    h2p = h2;
  }
}

extern "C" void kernel_launch(void* const* d_in, const int* in_sizes, int n_in,
                              void* d_out, int out_size, void* d_ws, size_t ws_size,
                              hipStream_t stream) {
  const float* x = (const float*)d_in[0];
  const float* wl = (const float*)d_in[1];
  const float* aw = (const float*)d_in[2];
  const float* ab = (const float*)d_in[3];
  const float* cw = (const float*)d_in[4];
  const float* noise = (const float*)d_in[5];
  const float* nstr = (const float*)d_in[6];
  const float* bias = (const float*)d_in[7];
  float* out = (float*)d_out;

  float* style = (float*)d_ws;
  float* dcoef = style + 8192;
  u16* W2 = (u16*)(dcoef + 8192);
  u16* xT = W2 + 4608 * 512;
  u16* Z = xT + (size_t)16384 * 512;

  k_style<<<dim3(8, 16), 256, 0, stream>>>(wl, aw, ab, style);
  k_wprep<<<dim3(512), 256, 0, stream>>>(cw, style, dcoef, W2);
  k_xt<<<dim3(16, 8, 16), 256, 0, stream>>>(x, style, xT);
  k_gemm<<<dim3(64, 18), 512, 0, stream>>>(W2, xT, Z);
  k_scatter<<<dim3(512, 16), 512, 0, stream>>>(Z, dcoef, noise, nstr, bias, out);
}

// Round 5
// 349.438 us; speedup vs baseline: 1.1241x; 1.0133x over previous
//
#include <hip/hip_runtime.h>
#include <hip/hip_bf16.h>

// SynthesisConv: style affine -> demod -> conv_transpose(up=2,k=3) -> FIR 4x4
// -> noise + bias + lrelu*sqrt(2) + clamp(+-256).  Inputs f32, output f32.
//
//   style folds into x (B-operand column scale), dcoef folds into epilogue.
//   Z[(o,ky,kx),(b,i,j)] = sum_c w[o,c,ky,kx] * x'[b,c,i,j]   (one shared GEMM)
// R7: k_gemm LDS chunk-swizzle kills the 8-way ds_read_b128 bank conflict.
// R8: 256x256 tile, BK=32, 4-buffer ring, counted vmcnt, setprio (null).
// R9: XCD swizzle (REGRESSED); k_style coalesced rewrite kept.
// R10: barriers 5->1 per K-tile + LDS-staged coalesced C-write (WIN).
// R11: k_scatter 512 thr same LDS -> 24 waves/CU (WIN: scatter off top-5).
// R12: k_gemm -> m201-style 8-phase fine interleave. BK=64, [buf][khalf]
//      double-buffered slabs, 4 phases/K-tile, each phase = {ds_read one
//      C-quadrant (4-8 b128) + stage one half-slab of kt+1 (2 gload_lds)
//      -> barrier -> lgkmcnt(0) -> 16 MFMA (setprio) -> barrier}; vmcnt(4)
//      2x per tile (never 0 mid-loop). 1-phase convoy serialized LDS port
//      (~1150cyc/tile/CU) against MFMA (~310cyc); fine interleave overlaps.

typedef unsigned short u16;
typedef unsigned int u32;
typedef u16 u16x8 __attribute__((ext_vector_type(8)));
typedef __bf16 bf16x8 __attribute__((ext_vector_type(8)));
typedef float f32x4 __attribute__((ext_vector_type(4)));

#define NB 16

__device__ __forceinline__ float bf2f(u16 v) {
  unsigned int u = ((unsigned int)v) << 16;
  float f;
  __builtin_memcpy(&f, &u, 4);
  return f;
}
__device__ __forceinline__ u16 f2bf(float f) {
  __hip_bfloat16 h = __float2bfloat16(f);  // RNE
  u16 r;
  __builtin_memcpy(&r, &h, 2);
  return r;
}
__device__ __forceinline__ void async16(u16* lds, const u16* g) {
  __builtin_amdgcn_global_load_lds(
      (const __attribute__((address_space(1))) u32*)g,
      (__attribute__((address_space(3))) u32*)lds, 16, 0, 0);
}

// ---- style[b,c] = sum_k wl[b,k]*aw[c,k]/sqrt(512) + ab[c] ---------------------
__global__ __launch_bounds__(256) void k_style(const float* __restrict__ wl,
                                               const float* __restrict__ aw,
                                               const float* __restrict__ ab,
                                               float* __restrict__ style) {
  __shared__ float lw[512];
  const int b = blockIdx.y;
  const int c0 = blockIdx.x << 6;
  const int t = threadIdx.x;
  for (int k = t; k < 512; k += 256) lw[k] = wl[b * 512 + k];
  __syncthreads();
  const int w = t >> 6, l = t & 63;
  const float4 lv0 = *(const float4*)(lw + (l << 2));
  const float4 lv1 = *(const float4*)(lw + 256 + (l << 2));
  for (int r = w; r < 64; r += 4) {
    const int c = c0 + r;
    const float* row = aw + (size_t)c * 512 + (l << 2);
    const float4 a0 = *(const float4*)(row);
    const float4 a1 = *(const float4*)(row + 256);
    float acc = lv0.x * a0.x + lv0.y * a0.y + lv0.z * a0.z + lv0.w * a0.w +
                lv1.x * a1.x + lv1.y * a1.y + lv1.z * a1.z + lv1.w * a1.w;
#pragma unroll
    for (int off = 32; off; off >>= 1) acc += __shfl_down(acc, off, 64);
    if (l == 0) style[b * 512 + c] = acc * 0.04419417382415922f + ab[c];
  }
}

// ---- merged: W2 pack (bf16, [o*9+kp][c]) + dcoef[b,o] ------------------------
__global__ __launch_bounds__(256) void k_wprep(const float* __restrict__ cw,
                                               const float* __restrict__ style,
                                               float* __restrict__ dcoef,
                                               u16* __restrict__ W2) {
  __shared__ u16 lw[4608];
  __shared__ float wsq[512];
  const int o = blockIdx.x, t = threadIdx.x;
  const float* src = cw + (size_t)o * 4608;
  for (int v = t; v < 4608; v += 256) {
    unsigned c = (unsigned)v / 9u;
    unsigned kp = (unsigned)v % 9u;
    lw[kp * 512 + c] = f2bf(src[v]);
  }
  for (int c = t; c < 512; c += 256) {
    const float* p = src + (size_t)c * 9;
    float s = 0.f;
#pragma unroll
    for (int k = 0; k < 9; ++k) {
      float v = p[k];
      s += v * v;
    }
    wsq[c] = s;
  }
  __syncthreads();
  u16* dst = W2 + (size_t)o * 4608;
  for (int v = t; v < 576; v += 256)
    *(u16x8*)(dst + v * 8) = *(const u16x8*)(lw + v * 8);
  const int w = t >> 6, l = t & 63;
  for (int b = w; b < NB; b += 4) {
    float part = 0.f;
#pragma unroll
    for (int c = l; c < 512; c += 64) {
      float st = style[b * 512 + c];
      part += st * st * wsq[c];
    }
#pragma unroll
    for (int off = 32; off; off >>= 1) part += __shfl_down(part, off, 64);
    if (l == 0) dcoef[b * 512 + o] = 1.0f / sqrtf(part + 1e-8f);
  }
}

// ---- xT[b,s,c] = bf16(x[b,c,s] * style[b,c])  (LDS 64x64 transpose) ----------
__global__ __launch_bounds__(256) void k_xt(const float* __restrict__ x,
                                            const float* __restrict__ style,
                                            u16* __restrict__ xT) {
  __shared__ u16 tile[64 * 66];
  const int b = blockIdx.z, c0 = blockIdx.y << 6, s0 = blockIdx.x << 6;
  const int t = threadIdx.x;
#pragma unroll
  for (int i = 0; i < 16; ++i) {
    int e = i * 256 + t;
    int cc = e >> 6, ss = e & 63;
    int c = c0 + cc;
    float v = x[(size_t)(b * 512 + c) * 1024 + s0 + ss] * style[b * 512 + c];
    tile[cc * 66 + ss] = f2bf(v);
  }
  __syncthreads();
#pragma unroll
  for (int e = 0; e < 2; ++e) {
    int idx = e * 256 + t;          // 512 = 64 rows x 8 col-groups
    int sc = idx >> 3;
    int cg = (idx & 7) << 3;
    u16x8 v;
#pragma unroll
    for (int g = 0; g < 8; ++g) v[g] = tile[(cg + g) * 66 + sc];
    *(u16x8*)(xT + (size_t)(b * 1024 + s0 + sc) * 512 + c0 + cg) = v;
  }
}

// ---- GEMM: Z[4608 x 16384] = W2[4608 x 512] * xT[16384 x 512]^T --------------
// R12: 256x256 tile, BK=64, 8 waves (2M x 4N, 128x64 C each), 16x16x32 MFMA.
// LDS: [buf 2][khalf 2] slabs of 256x32 per operand (128 KiB). 4 phases per
// K-tile: (rh,kh) in {(0,0),(1,0),(0,1),(1,1)}; each phase ds-reads its
// quadrant operands, issues one half-slab stage for kt+1, then barrier ->
// lgkmcnt(0) -> 16 MFMA -> barrier. vmcnt(4) at end of ph1 and ph3 only.
// R7 chunk swizzle per 32-k slab on both stage source and read side.
__global__ __launch_bounds__(512, 2) void k_gemm(const u16* __restrict__ W2,
                                                 const u16* __restrict__ xT,
                                                 u16* __restrict__ Z) {
  __shared__ union SM {
    struct { u16 A[2][2][8192]; u16 B[2][2][8192]; } g;  // [buf][kh][256r*32k]
    u16 C[256 * 264];                                    // 132 KiB epilogue
  } sm;
  const int t = threadIdx.x;
  const int m0 = blockIdx.y << 8;
  const int n0 = blockIdx.x << 8;
  const int l = t & 63;
  const int w = t >> 6;        // wave 0..7
  const int wm = w >> 2;       // 0..1  (M half: 128 rows)
  const int wn = w & 3;        // 0..3  (N quarter: 64 cols)
  const int lrow = l & 15;
  const int lk = l >> 4;       // k-chunk 0..3

  // staging: thread t covers slab row sr=t>>2, slot t&3; global source chunk
  // pre-swizzled (slot + (sr>>1)) & 3 within each 32-k group (R7 invariant).
  const int sr = t >> 2;
  const int sch = ((t & 3) + (sr >> 1)) & 3;
  const u16* gA = W2 + (size_t)(m0 + sr) * 512 + (sch << 3);
  const u16* gB = xT + (size_t)(n0 + sr) * 512 + (sch << 3);
  const int stg = t << 3;      // u16 offset in slab line0 (= sr*32 + slot*8)

  // read-side swizzled chunk offset: per-lane constant.
  const int sk8 = ((lk - (lrow >> 1)) & 3) << 3;
  const int arow = (wm << 7) + lrow;   // + rh*64 + i*16
  const int brow = (wn << 6) + lrow;   // + j*16

  f32x4 acc[8][4] = {};

#define STG_A(buf_, kh_, kt_)                                          \
  async16(&sm.g.A[buf_][kh_][stg], gA + (kt_) * 64 + (kh_) * 32);      \
  async16(&sm.g.A[buf_][kh_][4096 + stg],                              \
          gA + (kt_) * 64 + (kh_) * 32 + 128 * 512)
#define STG_B(buf_, kh_, kt_)                                          \
  async16(&sm.g.B[buf_][kh_][stg], gB + (kt_) * 64 + (kh_) * 32);      \
  async16(&sm.g.B[buf_][kh_][4096 + stg],                              \
          gB + (kt_) * 64 + (kh_) * 32 + 128 * 512)

  // prologue: tile 0's four half-stages in order A0,B0,A1,B1; retire A0,B0.
  STG_A(0, 0, 0);
  STG_B(0, 0, 0);
  STG_A(0, 1, 0);
  STG_B(0, 1, 0);
  asm volatile("s_waitcnt vmcnt(4)" ::: "memory");
  asm volatile("s_barrier" ::: "memory");

  for (int kt = 0; kt < 8; ++kt) {
    const int buf = kt & 1;
    const int nxt = buf ^ 1;
    const u16* Ak0 = sm.g.A[buf][0];
    const u16* Ak1 = sm.g.A[buf][1];
    const u16* Bk0 = sm.g.B[buf][0];
    const u16* Bk1 = sm.g.B[buf][1];
    bf16x8 av[4], bv[4];

    // ---- phase 0: (rh=0, kh=0) ----
#pragma unroll
    for (int i = 0; i < 4; ++i)
      av[i] = *(const bf16x8*)(Ak0 + (arow + i * 16) * 32 + sk8);
#pragma unroll
    for (int j = 0; j < 4; ++j)
      bv[j] = *(const bf16x8*)(Bk0 + (brow + j * 16) * 32 + sk8);
    if (kt < 7) { STG_A(nxt, 0, kt + 1); }
    asm volatile("s_barrier" ::: "memory");
    asm volatile("s_waitcnt lgkmcnt(0)" ::: "memory");
    __builtin_amdgcn_sched_barrier(0);
    __builtin_amdgcn_s_setprio(1);
#pragma unroll
    for (int i = 0; i < 4; ++i)
#pragma unroll
      for (int j = 0; j < 4; ++j)
        acc[i][j] = __builtin_amdgcn_mfma_f32_16x16x32_bf16(av[i], bv[j], acc[i][j], 0, 0, 0);
    __builtin_amdgcn_s_setprio(0);
    asm volatile("s_barrier" ::: "memory");

    // ---- phase 1: (rh=1, kh=0), bv reused ----
#pragma unroll
    for (int i = 0; i < 4; ++i)
      av[i] = *(const bf16x8*)(Ak0 + (arow + 64 + i * 16) * 32 + sk8);
    if (kt < 7) { STG_B(nxt, 0, kt + 1); }
    asm volatile("s_barrier" ::: "memory");
    asm volatile("s_waitcnt lgkmcnt(0)" ::: "memory");
    __builtin_amdgcn_sched_barrier(0);
    __builtin_amdgcn_s_setprio(1);
#pragma unroll
    for (int i = 0; i < 4; ++i)
#pragma unroll
      for (int j = 0; j < 4; ++j)
        acc[i + 4][j] = __builtin_amdgcn_mfma_f32_16x16x32_bf16(av[i], bv[j], acc[i + 4][j], 0, 0, 0);
    __builtin_amdgcn_s_setprio(0);
    // retire this tile's kh=1 half-stages (issued during kt-1 ph2/ph3).
    if (kt < 7) {
      asm volatile("s_waitcnt vmcnt(4)" ::: "memory");
    } else {
      asm volatile("s_waitcnt vmcnt(0)" ::: "memory");
    }
    asm volatile("s_barrier" ::: "memory");

    // ---- phase 2: (rh=0, kh=1) ----
#pragma unroll
    for (int i = 0; i < 4; ++i)
      av[i] = *(const bf16x8*)(Ak1 + (arow + i * 16) * 32 + sk8);
#pragma unroll
    for (int j = 0; j < 4; ++j)
      bv[j] = *(const bf16x8*)(Bk1 + (brow + j * 16) * 32 + sk8);
    if (kt < 7) { STG_A(nxt, 1, kt + 1); }
    asm volatile("s_barrier" ::: "memory");
    asm volatile("s_waitcnt lgkmcnt(0)" ::: "memory");
    __builtin_amdgcn_sched_barrier(0);
    __builtin_amdgcn_s_setprio(1);
#pragma unroll
    for (int i = 0; i < 4; ++i)
#pragma unroll
      for (int j = 0; j < 4; ++j)
        acc[i][j] = __builtin_amdgcn_mfma_f32_16x16x32_bf16(av[i], bv[j], acc[i][j], 0, 0, 0);
    __builtin_amdgcn_s_setprio(0);
    asm volatile("s_barrier" ::: "memory");

    // ---- phase 3: (rh=1, kh=1), bv reused ----
#pragma unroll
    for (int i = 0; i < 4; ++i)
      av[i] = *(const bf16x8*)(Ak1 + (arow + 64 + i * 16) * 32 + sk8);
    if (kt < 7) { STG_B(nxt, 1, kt + 1); }
    asm volatile("s_barrier" ::: "memory");
    asm volatile("s_waitcnt lgkmcnt(0)" ::: "memory");
    __builtin_amdgcn_sched_barrier(0);
    __builtin_amdgcn_s_setprio(1);
#pragma unroll
    for (int i = 0; i < 4; ++i)
#pragma unroll
      for (int j = 0; j < 4; ++j)
        acc[i + 4][j] = __builtin_amdgcn_mfma_f32_16x16x32_bf16(av[i], bv[j], acc[i + 4][j], 0, 0, 0);
    __builtin_amdgcn_s_setprio(0);
    // retire next tile's kh=0 half-stages (issued this tile ph0/ph1).
    if (kt < 7) {
      asm volatile("s_waitcnt vmcnt(4)" ::: "memory");
    }
    asm volatile("s_barrier" ::: "memory");
  }
#undef STG_A
#undef STG_B

  __syncthreads();  // ring dead; reuse LDS as C tile
  const int crow0 = (wm << 7) + (lk << 2);
  const int ccol0 = (wn << 6) + lrow;
#pragma unroll
  for (int i = 0; i < 8; ++i)
#pragma unroll
    for (int j = 0; j < 4; ++j)
#pragma unroll
      for (int r = 0; r < 4; ++r)
        sm.C[(crow0 + i * 16 + r) * 264 + ccol0 + j * 16] = f2bf(acc[i][j][r]);
  __syncthreads();
  u16* zb = Z + (size_t)m0 * 16384 + n0;
#pragma unroll
  for (int k = 0; k < 16; ++k) {
    int c = (k << 9) | t;
    int row = c >> 5;
    int c8 = (c & 31) << 3;
    *(u16x8*)(zb + (size_t)row * 16384 + c8) = *(const u16x8*)(sm.C + row * 264 + c8);
  }
}

// ---- scatter: polyphase separable FIR + epilogue -----------------------------
__global__ __launch_bounds__(512) void k_scatter(
    const u16* __restrict__ Z, const float* __restrict__ dcoef,
    const float* __restrict__ noise, const float* __restrict__ nstr,
    const float* __restrict__ bias, float* __restrict__ out) {
  __shared__ u16 Zl[9 * 1024];
  __shared__ float Hl[3 * 2048];
  const int o = blockIdx.x;
  const int b = blockIdx.y;
  const int t = threadIdx.x;
  const u16* Zp = Z + (size_t)o * 9 * 16384 + (size_t)b * 1024;
  for (int v = t; v < 1152; v += 512) {
    int kp = v >> 7, off = (v & 127) << 3;
    *(u16x8*)(Zl + kp * 1024 + off) = *(const u16x8*)(Zp + (size_t)kp * 16384 + off);
  }
  __syncthreads();
#pragma unroll
  for (int e = 0; e < 6; ++e) {
    int idx = e * 512 + t;
    int ky = idx >> 10;
    int i = (idx >> 5) & 31;
    int j = idx & 31;
    const u16* P0 = Zl + (ky * 3 + 0) * 1024 + i * 32;
    const u16* P1 = P0 + 1024;
    const u16* P2 = P0 + 2048;
    float Ej = bf2f(P0[j]) + (j >= 1 ? bf2f(P2[j - 1]) : 0.f);
    float Ej1 = (j < 31 ? bf2f(P0[j + 1]) : 0.f) + bf2f(P2[j]);
    float Ojm = j >= 1 ? bf2f(P1[j - 1]) : 0.f;
    float Oj = bf2f(P1[j]);
    float Ojp = j < 31 ? bf2f(P1[j + 1]) : 0.f;
    float* hp = Hl + ky * 2048 + i * 64 + j;
    hp[0] = Ojm + 3.f * Ej + 3.f * Oj + Ej1;
    hp[32] = Ej + 3.f * Oj + 3.f * Ej1 + Ojp;
  }
  __syncthreads();
  const float dc = dcoef[b * 512 + o] * 0.0625f;
  const float ns = nstr[0];
  const float bo = bias[o];
  const int n = t & 63;
  const int i0 = (t >> 6) << 2;   // 8 groups x 4 rows
  const int sw = ((n & 1) << 5) | (n >> 1);
  const float* H0 = Hl + sw;
  const float* H1 = Hl + 2048 + sw;
  const float* H2 = Hl + 4096 + sw;
  float h0 = H0[i0 * 64];
  float h1 = H1[i0 * 64];
  float h1p = (i0 > 0) ? H1[(i0 - 1) * 64] : 0.f;
  float h2p = (i0 > 0) ? H2[(i0 - 1) * 64] : 0.f;
  const float* nz = noise + ((size_t)b << 12) + n;
  float* op = out + (((size_t)(b * 512 + o)) << 12) + n;
#pragma unroll
  for (int s = 0; s < 4; ++s) {
    int i = i0 + s;
    float h0n = (i < 31) ? H0[(i + 1) * 64] : 0.f;
    float h1n = (i < 31) ? H1[(i + 1) * 64] : 0.f;
    float h2 = H2[i * 64];
    float ev = h1p + 3.f * (h0 + h2p) + 3.f * h1 + (h0n + h2);
    float od = (h0 + h2p) + 3.f * h1 + 3.f * (h0n + h2) + h1n;
    int m = 2 * i;
    float v0 = ev * dc + nz[(size_t)m * 64] * ns + bo;
    v0 = (v0 > 0.f ? v0 : 0.2f * v0) * 1.4142135623730951f;
    v0 = fminf(fmaxf(v0, -256.f), 256.f);
    op[(size_t)m * 64] = v0;
    float v1 = od * dc + nz[(size_t)(m + 1) * 64] * ns + bo;
    v1 = (v1 > 0.f ? v1 : 0.2f * v1) * 1.4142135623730951f;
    v1 = fminf(fmaxf(v1, -256.f), 256.f);
    op[(size_t)(m + 1) * 64] = v1;
    h0 = h0n;
    h1p = h1;
    h1 = h1n;
    h2p = h2;
  }
}

extern "C" void kernel_launch(void* const* d_in, const int* in_sizes, int n_in,
                              void* d_out, int out_size, void* d_ws, size_t ws_size,
                              hipStream_t stream) {
  const float* x = (const float*)d_in[0];
  const float* wl = (const float*)d_in[1];
  const float* aw = (const float*)d_in[2];
  const float* ab = (const float*)d_in[3];
  const float* cw = (const float*)d_in[4];
  const float* noise = (const float*)d_in[5];
  const float* nstr = (const float*)d_in[6];
  const float* bias = (const float*)d_in[7];
  float* out = (float*)d_out;

  float* style = (float*)d_ws;
  float* dcoef = style + 8192;
  u16* W2 = (u16*)(dcoef + 8192);
  u16* xT = W2 + 4608 * 512;
  u16* Z = xT + (size_t)16384 * 512;

  k_style<<<dim3(8, 16), 256, 0, stream>>>(wl, aw, ab, style);
  k_wprep<<<dim3(512), 256, 0, stream>>>(cw, style, dcoef, W2);
  k_xt<<<dim3(16, 8, 16), 256, 0, stream>>>(x, style, xT);
  k_gemm<<<dim3(64, 18), 512, 0, stream>>>(W2, xT, Z);
  k_scatter<<<dim3(512, 16), 512, 0, stream>>>(Z, dcoef, noise, nstr, bias, out);
}

// Round 6
// 338.251 us; speedup vs baseline: 1.1613x; 1.0331x over previous
//
#include <hip/hip_runtime.h>
#include <hip/hip_bf16.h>

// SynthesisConv: style affine -> demod -> conv_transpose(up=2,k=3) -> FIR 4x4
// -> noise + bias + lrelu*sqrt(2) + clamp(+-256).  Inputs f32, output f32.
//
//   style folds into x (B-operand column scale), dcoef folds into epilogue.
//   Z[(o,ky,kx),(b,i,j)] = sum_c w[o,c,ky,kx] * x'[b,c,i,j]   (one shared GEMM)
// R7: k_gemm LDS chunk-swizzle kills the 8-way ds_read_b128 bank conflict.
// R8: 256x256, 4-buffer ring, counted vmcnt, setprio (null).
// R9: XCD swizzle (REGRESSED); k_style coalesced rewrite kept.
// R10: barriers 5->1 per K-tile + LDS-staged coalesced C-write (WIN).
// R11: k_scatter 512 thr -> 24 waves/CU (WIN).
// R12: m201-style 4-phase fine interleave (null: 4th schedule at ~30% MfmaUtil
//      -> schedule family exhausted; invariant is 1 block/CU: the 128KB+ LDS
//      forces serial per-block epilogue (7.5us global C-write, MFMA dead) and
//      2 waves/SIMD latency hiding).
// R13: k_gemm -> 128x256 tile, wave 64x64 (acc 64 VGPR), BK=32, 3-buf ring,
//      72 KiB LDS, launch_bounds(512,4) caps VGPR<=128 -> 2 blocks/CU,
//      16 waves/CU: block A's epilogue/stalls overlap block B's MFMA.
//      Discriminates epilogue-serialization vs LDS-BW theories.

typedef unsigned short u16;
typedef unsigned int u32;
typedef u16 u16x8 __attribute__((ext_vector_type(8)));
typedef __bf16 bf16x8 __attribute__((ext_vector_type(8)));
typedef float f32x4 __attribute__((ext_vector_type(4)));

#define NB 16

__device__ __forceinline__ float bf2f(u16 v) {
  unsigned int u = ((unsigned int)v) << 16;
  float f;
  __builtin_memcpy(&f, &u, 4);
  return f;
}
__device__ __forceinline__ u16 f2bf(float f) {
  __hip_bfloat16 h = __float2bfloat16(f);  // RNE
  u16 r;
  __builtin_memcpy(&r, &h, 2);
  return r;
}
__device__ __forceinline__ void async16(u16* lds, const u16* g) {
  __builtin_amdgcn_global_load_lds(
      (const __attribute__((address_space(1))) u32*)g,
      (__attribute__((address_space(3))) u32*)lds, 16, 0, 0);
}

// ---- style[b,c] = sum_k wl[b,k]*aw[c,k]/sqrt(512) + ab[c] ---------------------
__global__ __launch_bounds__(256) void k_style(const float* __restrict__ wl,
                                               const float* __restrict__ aw,
                                               const float* __restrict__ ab,
                                               float* __restrict__ style) {
  __shared__ float lw[512];
  const int b = blockIdx.y;
  const int c0 = blockIdx.x << 6;
  const int t = threadIdx.x;
  for (int k = t; k < 512; k += 256) lw[k] = wl[b * 512 + k];
  __syncthreads();
  const int w = t >> 6, l = t & 63;
  const float4 lv0 = *(const float4*)(lw + (l << 2));
  const float4 lv1 = *(const float4*)(lw + 256 + (l << 2));
  for (int r = w; r < 64; r += 4) {
    const int c = c0 + r;
    const float* row = aw + (size_t)c * 512 + (l << 2);
    const float4 a0 = *(const float4*)(row);
    const float4 a1 = *(const float4*)(row + 256);
    float acc = lv0.x * a0.x + lv0.y * a0.y + lv0.z * a0.z + lv0.w * a0.w +
                lv1.x * a1.x + lv1.y * a1.y + lv1.z * a1.z + lv1.w * a1.w;
#pragma unroll
    for (int off = 32; off; off >>= 1) acc += __shfl_down(acc, off, 64);
    if (l == 0) style[b * 512 + c] = acc * 0.04419417382415922f + ab[c];
  }
}

// ---- merged: W2 pack (bf16, [o*9+kp][c]) + dcoef[b,o] ------------------------
__global__ __launch_bounds__(256) void k_wprep(const float* __restrict__ cw,
                                               const float* __restrict__ style,
                                               float* __restrict__ dcoef,
                                               u16* __restrict__ W2) {
  __shared__ u16 lw[4608];
  __shared__ float wsq[512];
  const int o = blockIdx.x, t = threadIdx.x;
  const float* src = cw + (size_t)o * 4608;
  for (int v = t; v < 4608; v += 256) {
    unsigned c = (unsigned)v / 9u;
    unsigned kp = (unsigned)v % 9u;
    lw[kp * 512 + c] = f2bf(src[v]);
  }
  for (int c = t; c < 512; c += 256) {
    const float* p = src + (size_t)c * 9;
    float s = 0.f;
#pragma unroll
    for (int k = 0; k < 9; ++k) {
      float v = p[k];
      s += v * v;
    }
    wsq[c] = s;
  }
  __syncthreads();
  u16* dst = W2 + (size_t)o * 4608;
  for (int v = t; v < 576; v += 256)
    *(u16x8*)(dst + v * 8) = *(const u16x8*)(lw + v * 8);
  const int w = t >> 6, l = t & 63;
  for (int b = w; b < NB; b += 4) {
    float part = 0.f;
#pragma unroll
    for (int c = l; c < 512; c += 64) {
      float st = style[b * 512 + c];
      part += st * st * wsq[c];
    }
#pragma unroll
    for (int off = 32; off; off >>= 1) part += __shfl_down(part, off, 64);
    if (l == 0) dcoef[b * 512 + o] = 1.0f / sqrtf(part + 1e-8f);
  }
}

// ---- xT[b,s,c] = bf16(x[b,c,s] * style[b,c])  (LDS 64x64 transpose) ----------
__global__ __launch_bounds__(256) void k_xt(const float* __restrict__ x,
                                            const float* __restrict__ style,
                                            u16* __restrict__ xT) {
  __shared__ u16 tile[64 * 66];
  const int b = blockIdx.z, c0 = blockIdx.y << 6, s0 = blockIdx.x << 6;
  const int t = threadIdx.x;
#pragma unroll
  for (int i = 0; i < 16; ++i) {
    int e = i * 256 + t;
    int cc = e >> 6, ss = e & 63;
    int c = c0 + cc;
    float v = x[(size_t)(b * 512 + c) * 1024 + s0 + ss] * style[b * 512 + c];
    tile[cc * 66 + ss] = f2bf(v);
  }
  __syncthreads();
#pragma unroll
  for (int e = 0; e < 2; ++e) {
    int idx = e * 256 + t;          // 512 = 64 rows x 8 col-groups
    int sc = idx >> 3;
    int cg = (idx & 7) << 3;
    u16x8 v;
#pragma unroll
    for (int g = 0; g < 8; ++g) v[g] = tile[(cg + g) * 66 + sc];
    *(u16x8*)(xT + (size_t)(b * 1024 + s0 + sc) * 512 + c0 + cg) = v;
  }
}

// ---- GEMM: Z[4608 x 16384] = W2[4608 x 512] * xT[16384 x 512]^T --------------
// R13: 128x256 tile, BK=32, 8 waves (2M x 4N, wave tile 64x64, acc[4][4]).
// 3-buffer ring (A 8KB + B 16KB per buf = 72 KiB), 2-tile-deep prefetch,
// counted vmcnt(3) ladder, 1 barrier/tile, setprio. 2 blocks/CU.
// R7 chunk swizzle on stage source + read side. C via LDS [128][264] union.
__global__ __launch_bounds__(512, 4) void k_gemm(const u16* __restrict__ W2,
                                                 const u16* __restrict__ xT,
                                                 u16* __restrict__ Z) {
  __shared__ union SM {
    struct { u16 A[3][4096]; u16 B[3][8192]; } g;  // 72 KiB ring
    u16 C[128 * 264];                              // 66 KiB epilogue tile
  } sm;
  const int t = threadIdx.x;
  const int m0 = blockIdx.y << 7;   // 36 m-blocks
  const int n0 = blockIdx.x << 8;   // 64 n-blocks
  const int l = t & 63;
  const int w = t >> 6;        // wave 0..7
  const int wm = w >> 2;       // 0..1  (M half: 64 rows)
  const int wn = w & 3;        // 0..3  (N quarter: 64 cols)
  const int lrow = l & 15;
  const int lk = l >> 4;       // k-chunk 0..3

  // staging: thread t covers slab row sr=t>>2 (0..127), slot t&3; global
  // source chunk pre-swizzled (slot + (sr>>1)) & 3 (R7 invariant).
  const int sr = t >> 2;
  const int sch = ((t & 3) + (sr >> 1)) & 3;
  const u16* gA = W2 + (size_t)(m0 + sr) * 512 + (sch << 3);
  const u16* gB = xT + (size_t)(n0 + sr) * 512 + (sch << 3);
  const int stg = t << 3;      // u16 offset in 8 KB slab

  // read-side swizzled chunk offset: per-lane constant (rows are 16-aligned
  // bases + lrow, so (row>>1)&3 folds to lrow>>1).
  const int sk8 = ((lk - (lrow >> 1)) & 3) << 3;
  const int arow = (wm << 6) + lrow;
  const int brow = (wn << 6) + lrow;

  f32x4 acc[4][4] = {};

  // one K-tile stage = 3 async16: A rows 0-127, B rows 0-127, B rows 128-255
#define STG(buf_, kt_)                                              \
  async16(&sm.g.A[buf_][stg], gA + (kt_) * 32);                     \
  async16(&sm.g.B[buf_][stg], gB + (kt_) * 32);                     \
  async16(&sm.g.B[buf_][4096 + stg], gB + (kt_) * 32 + 128 * 512)

  // prologue: tiles 0,1 in flight (6 loads); retire tile 0's 3 (counted).
  STG(0, 0);
  STG(1, 1);
  asm volatile("s_waitcnt vmcnt(3)" ::: "memory");
  asm volatile("s_barrier" ::: "memory");

  int buf = 0, nxt = 2;
  for (int kt = 0; kt < 16; ++kt) {
    const u16* Ab = sm.g.A[buf];
    const u16* Bb = sm.g.B[buf];
    bf16x8 av[4], bv[4];
#pragma unroll
    for (int i = 0; i < 4; ++i)
      av[i] = *(const bf16x8*)(Ab + (arow + i * 16) * 32 + sk8);
#pragma unroll
    for (int j = 0; j < 4; ++j)
      bv[j] = *(const bf16x8*)(Bb + (brow + j * 16) * 32 + sk8);
    if (kt < 14) { STG(nxt, kt + 2); }
    asm volatile("s_waitcnt lgkmcnt(0)" ::: "memory");
    __builtin_amdgcn_sched_barrier(0);
    __builtin_amdgcn_s_setprio(1);
#pragma unroll
    for (int i = 0; i < 4; ++i)
#pragma unroll
      for (int j = 0; j < 4; ++j)
        acc[i][j] = __builtin_amdgcn_mfma_f32_16x16x32_bf16(av[i], bv[j], acc[i][j], 0, 0, 0);
    __builtin_amdgcn_s_setprio(0);
    // tile boundary: retire tile kt+1's 3 loads; keep kt+2's in flight.
    if (kt <= 13) {
      asm volatile("s_waitcnt vmcnt(3)" ::: "memory");
    } else if (kt == 14) {
      asm volatile("s_waitcnt vmcnt(0)" ::: "memory");
    }
    asm volatile("s_barrier" ::: "memory");
    buf = (buf == 2) ? 0 : buf + 1;
    nxt = (nxt == 2) ? 0 : nxt + 1;
  }
#undef STG

  __syncthreads();  // ring dead; reuse LDS as C tile
  const int crow0 = (wm << 6) + (lk << 2);
  const int ccol0 = (wn << 6) + lrow;
#pragma unroll
  for (int i = 0; i < 4; ++i)
#pragma unroll
    for (int j = 0; j < 4; ++j)
#pragma unroll
      for (int r = 0; r < 4; ++r)
        sm.C[(crow0 + i * 16 + r) * 264 + ccol0 + j * 16] = f2bf(acc[i][j][r]);
  __syncthreads();
  // coalesced Z stores: 128 rows x 32 chunks of 16B; 8 chunks per thread.
  u16* zb = Z + (size_t)m0 * 16384 + n0;
#pragma unroll
  for (int k = 0; k < 8; ++k) {
    int c = (k << 9) | t;
    int row = c >> 5;
    int c8 = (c & 31) << 3;
    *(u16x8*)(zb + (size_t)row * 16384 + c8) = *(const u16x8*)(sm.C + row * 264 + c8);
  }
}

// ---- scatter: polyphase separable FIR + epilogue -----------------------------
__global__ __launch_bounds__(512) void k_scatter(
    const u16* __restrict__ Z, const float* __restrict__ dcoef,
    const float* __restrict__ noise, const float* __restrict__ nstr,
    const float* __restrict__ bias, float* __restrict__ out) {
  __shared__ u16 Zl[9 * 1024];
  __shared__ float Hl[3 * 2048];
  const int o = blockIdx.x;
  const int b = blockIdx.y;
  const int t = threadIdx.x;
  const u16* Zp = Z + (size_t)o * 9 * 16384 + (size_t)b * 1024;
  for (int v = t; v < 1152; v += 512) {
    int kp = v >> 7, off = (v & 127) << 3;
    *(u16x8*)(Zl + kp * 1024 + off) = *(const u16x8*)(Zp + (size_t)kp * 16384 + off);
  }
  __syncthreads();
#pragma unroll
  for (int e = 0; e < 6; ++e) {
    int idx = e * 512 + t;
    int ky = idx >> 10;
    int i = (idx >> 5) & 31;
    int j = idx & 31;
    const u16* P0 = Zl + (ky * 3 + 0) * 1024 + i * 32;
    const u16* P1 = P0 + 1024;
    const u16* P2 = P0 + 2048;
    float Ej = bf2f(P0[j]) + (j >= 1 ? bf2f(P2[j - 1]) : 0.f);
    float Ej1 = (j < 31 ? bf2f(P0[j + 1]) : 0.f) + bf2f(P2[j]);
    float Ojm = j >= 1 ? bf2f(P1[j - 1]) : 0.f;
    float Oj = bf2f(P1[j]);
    float Ojp = j < 31 ? bf2f(P1[j + 1]) : 0.f;
    float* hp = Hl + ky * 2048 + i * 64 + j;
    hp[0] = Ojm + 3.f * Ej + 3.f * Oj + Ej1;
    hp[32] = Ej + 3.f * Oj + 3.f * Ej1 + Ojp;
  }
  __syncthreads();
  const float dc = dcoef[b * 512 + o] * 0.0625f;
  const float ns = nstr[0];
  const float bo = bias[o];
  const int n = t & 63;
  const int i0 = (t >> 6) << 2;   // 8 groups x 4 rows
  const int sw = ((n & 1) << 5) | (n >> 1);
  const float* H0 = Hl + sw;
  const float* H1 = Hl + 2048 + sw;
  const float* H2 = Hl + 4096 + sw;
  float h0 = H0[i0 * 64];
  float h1 = H1[i0 * 64];
  float h1p = (i0 > 0) ? H1[(i0 - 1) * 64] : 0.f;
  float h2p = (i0 > 0) ? H2[(i0 - 1) * 64] : 0.f;
  const float* nz = noise + ((size_t)b << 12) + n;
  float* op = out + (((size_t)(b * 512 + o)) << 12) + n;
#pragma unroll
  for (int s = 0; s < 4; ++s) {
    int i = i0 + s;
    float h0n = (i < 31) ? H0[(i + 1) * 64] : 0.f;
    float h1n = (i < 31) ? H1[(i + 1) * 64] : 0.f;
    float h2 = H2[i * 64];
    float ev = h1p + 3.f * (h0 + h2p) + 3.f * h1 + (h0n + h2);
    float od = (h0 + h2p) + 3.f * h1 + 3.f * (h0n + h2) + h1n;
    int m = 2 * i;
    float v0 = ev * dc + nz[(size_t)m * 64] * ns + bo;
    v0 = (v0 > 0.f ? v0 : 0.2f * v0) * 1.4142135623730951f;
    v0 = fminf(fmaxf(v0, -256.f), 256.f);
    op[(size_t)m * 64] = v0;
    float v1 = od * dc + nz[(size_t)(m + 1) * 64] * ns + bo;
    v1 = (v1 > 0.f ? v1 : 0.2f * v1) * 1.4142135623730951f;
    v1 = fminf(fmaxf(v1, -256.f), 256.f);
    op[(size_t)(m + 1) * 64] = v1;
    h0 = h0n;
    h1p = h1;
    h1 = h1n;
    h2p = h2;
  }
}

extern "C" void kernel_launch(void* const* d_in, const int* in_sizes, int n_in,
                              void* d_out, int out_size, void* d_ws, size_t ws_size,
                              hipStream_t stream) {
  const float* x = (const float*)d_in[0];
  const float* wl = (const float*)d_in[1];
  const float* aw = (const float*)d_in[2];
  const float* ab = (const float*)d_in[3];
  const float* cw = (const float*)d_in[4];
  const float* noise = (const float*)d_in[5];
  const float* nstr = (const float*)d_in[6];
  const float* bias = (const float*)d_in[7];
  float* out = (float*)d_out;

  float* style = (float*)d_ws;
  float* dcoef = style + 8192;
  u16* W2 = (u16*)(dcoef + 8192);
  u16* xT = W2 + 4608 * 512;
  u16* Z = xT + (size_t)16384 * 512;

  k_style<<<dim3(8, 16), 256, 0, stream>>>(wl, aw, ab, style);
  k_wprep<<<dim3(512), 256, 0, stream>>>(cw, style, dcoef, W2);
  k_xt<<<dim3(16, 8, 16), 256, 0, stream>>>(x, style, xT);
  k_gemm<<<dim3(64, 36), 512, 0, stream>>>(W2, xT, Z);
  k_scatter<<<dim3(512, 16), 512, 0, stream>>>(Z, dcoef, noise, nstr, bias, out);
}

// Round 7
// 320.824 us; speedup vs baseline: 1.2244x; 1.0543x over previous
//
#include <hip/hip_runtime.h>
#include <hip/hip_bf16.h>

// SynthesisConv: style affine -> demod -> conv_transpose(up=2,k=3) -> FIR 4x4
// -> noise + bias + lrelu*sqrt(2) + clamp(+-256).  Inputs f32, output f32.
//
//   style folds into x (B-operand column scale), dcoef folds into epilogue.
//   Z[(o,ky,kx),(b,i,j)] = sum_c w[o,c,ky,kx] * x'[b,c,i,j]   (one shared GEMM)
// R7: k_gemm LDS chunk-swizzle kills the 8-way ds_read_b128 bank conflict.
// R8: 256x256, 4-buffer ring, counted vmcnt, setprio (null).
// R9: XCD swizzle (REGRESSED); k_style coalesced rewrite kept.
// R10: barriers 5->1 per K-tile + LDS-staged coalesced C-write (WIN).
// R11: k_scatter 512 thr -> 24 waves/CU (WIN).
// R12: m201-style 4-phase fine interleave (null; schedule family exhausted).
// R13: k_gemm 128x256, 2 blocks/CU (WIN: 102.8->92.9, Occ 18->39%; gemm now
//      mixed LDS/MFMA regime). gemm rests; scatter (~86, hidden) + xt (~45,
//      16 scalar 4B loads/thread) are the untouched co-bottlenecks.
// R14: k_scatter phase-3 rewrite: 1 thread per (i, j-quad), float2 H reads,
//      float4 noise loads, 2x float4 out stores (was 8 scalar 4B stores +
//      serial rolling chain). k_xt loads float4 (4x fewer, 16B/lane).

typedef unsigned short u16;
typedef unsigned int u32;
typedef u16 u16x2 __attribute__((ext_vector_type(2)));
typedef u16 u16x8 __attribute__((ext_vector_type(8)));
typedef __bf16 bf16x8 __attribute__((ext_vector_type(8)));
typedef float f32x4 __attribute__((ext_vector_type(4)));

#define NB 16

__device__ __forceinline__ float bf2f(u16 v) {
  unsigned int u = ((unsigned int)v) << 16;
  float f;
  __builtin_memcpy(&f, &u, 4);
  return f;
}
__device__ __forceinline__ u16 f2bf(float f) {
  __hip_bfloat16 h = __float2bfloat16(f);  // RNE
  u16 r;
  __builtin_memcpy(&r, &h, 2);
  return r;
}
__device__ __forceinline__ void async16(u16* lds, const u16* g) {
  __builtin_amdgcn_global_load_lds(
      (const __attribute__((address_space(1))) u32*)g,
      (__attribute__((address_space(3))) u32*)lds, 16, 0, 0);
}

// ---- style[b,c] = sum_k wl[b,k]*aw[c,k]/sqrt(512) + ab[c] ---------------------
__global__ __launch_bounds__(256) void k_style(const float* __restrict__ wl,
                                               const float* __restrict__ aw,
                                               const float* __restrict__ ab,
                                               float* __restrict__ style) {
  __shared__ float lw[512];
  const int b = blockIdx.y;
  const int c0 = blockIdx.x << 6;
  const int t = threadIdx.x;
  for (int k = t; k < 512; k += 256) lw[k] = wl[b * 512 + k];
  __syncthreads();
  const int w = t >> 6, l = t & 63;
  const float4 lv0 = *(const float4*)(lw + (l << 2));
  const float4 lv1 = *(const float4*)(lw + 256 + (l << 2));
  for (int r = w; r < 64; r += 4) {
    const int c = c0 + r;
    const float* row = aw + (size_t)c * 512 + (l << 2);
    const float4 a0 = *(const float4*)(row);
    const float4 a1 = *(const float4*)(row + 256);
    float acc = lv0.x * a0.x + lv0.y * a0.y + lv0.z * a0.z + lv0.w * a0.w +
                lv1.x * a1.x + lv1.y * a1.y + lv1.z * a1.z + lv1.w * a1.w;
#pragma unroll
    for (int off = 32; off; off >>= 1) acc += __shfl_down(acc, off, 64);
    if (l == 0) style[b * 512 + c] = acc * 0.04419417382415922f + ab[c];
  }
}

// ---- merged: W2 pack (bf16, [o*9+kp][c]) + dcoef[b,o] ------------------------
__global__ __launch_bounds__(256) void k_wprep(const float* __restrict__ cw,
                                               const float* __restrict__ style,
                                               float* __restrict__ dcoef,
                                               u16* __restrict__ W2) {
  __shared__ u16 lw[4608];
  __shared__ float wsq[512];
  const int o = blockIdx.x, t = threadIdx.x;
  const float* src = cw + (size_t)o * 4608;
  for (int v = t; v < 4608; v += 256) {
    unsigned c = (unsigned)v / 9u;
    unsigned kp = (unsigned)v % 9u;
    lw[kp * 512 + c] = f2bf(src[v]);
  }
  for (int c = t; c < 512; c += 256) {
    const float* p = src + (size_t)c * 9;
    float s = 0.f;
#pragma unroll
    for (int k = 0; k < 9; ++k) {
      float v = p[k];
      s += v * v;
    }
    wsq[c] = s;
  }
  __syncthreads();
  u16* dst = W2 + (size_t)o * 4608;
  for (int v = t; v < 576; v += 256)
    *(u16x8*)(dst + v * 8) = *(const u16x8*)(lw + v * 8);
  const int w = t >> 6, l = t & 63;
  for (int b = w; b < NB; b += 4) {
    float part = 0.f;
#pragma unroll
    for (int c = l; c < 512; c += 64) {
      float st = style[b * 512 + c];
      part += st * st * wsq[c];
    }
#pragma unroll
    for (int off = 32; off; off >>= 1) part += __shfl_down(part, off, 64);
    if (l == 0) dcoef[b * 512 + o] = 1.0f / sqrtf(part + 1e-8f);
  }
}

// ---- xT[b,s,c] = bf16(x[b,c,s] * style[b,c])  (LDS 64x64 transpose) ----------
// R14: float4 loads (16B/lane, 4 iters) instead of 16 scalar 4B loads.
__global__ __launch_bounds__(256) void k_xt(const float* __restrict__ x,
                                            const float* __restrict__ style,
                                            u16* __restrict__ xT) {
  __shared__ u16 tile[64 * 66];
  const int b = blockIdx.z, c0 = blockIdx.y << 6, s0 = blockIdx.x << 6;
  const int t = threadIdx.x;
#pragma unroll
  for (int i = 0; i < 4; ++i) {
    int e = i * 256 + t;
    int cc = e >> 4, f4 = e & 15;   // 64 rows x 16 float4
    int c = c0 + cc;
    float4 v = *(const float4*)(x + (size_t)(b * 512 + c) * 1024 + s0 + f4 * 4);
    float sv = style[b * 512 + c];
    int base = cc * 66 + f4 * 4;    // even -> 4B aligned for u16x2
    u16x2 p0, p1;
    p0[0] = f2bf(v.x * sv);
    p0[1] = f2bf(v.y * sv);
    p1[0] = f2bf(v.z * sv);
    p1[1] = f2bf(v.w * sv);
    *(u16x2*)(tile + base) = p0;
    *(u16x2*)(tile + base + 2) = p1;
  }
  __syncthreads();
#pragma unroll
  for (int e = 0; e < 2; ++e) {
    int idx = e * 256 + t;          // 512 = 64 rows x 8 col-groups
    int sc = idx >> 3;
    int cg = (idx & 7) << 3;
    u16x8 v;
#pragma unroll
    for (int g = 0; g < 8; ++g) v[g] = tile[(cg + g) * 66 + sc];
    *(u16x8*)(xT + (size_t)(b * 1024 + s0 + sc) * 512 + c0 + cg) = v;
  }
}

// ---- GEMM: Z[4608 x 16384] = W2[4608 x 512] * xT[16384 x 512]^T --------------
// R13: 128x256 tile, BK=32, 8 waves (2M x 4N, wave tile 64x64, acc[4][4]).
// 3-buffer ring, 2-tile-deep prefetch, counted vmcnt(3), 1 barrier/tile,
// setprio. 2 blocks/CU. R7 chunk swizzle. C via LDS [128][264] union.
__global__ __launch_bounds__(512, 4) void k_gemm(const u16* __restrict__ W2,
                                                 const u16* __restrict__ xT,
                                                 u16* __restrict__ Z) {
  __shared__ union SM {
    struct { u16 A[3][4096]; u16 B[3][8192]; } g;  // 72 KiB ring
    u16 C[128 * 264];                              // 66 KiB epilogue tile
  } sm;
  const int t = threadIdx.x;
  const int m0 = blockIdx.y << 7;   // 36 m-blocks
  const int n0 = blockIdx.x << 8;   // 64 n-blocks
  const int l = t & 63;
  const int w = t >> 6;        // wave 0..7
  const int wm = w >> 2;       // 0..1  (M half: 64 rows)
  const int wn = w & 3;        // 0..3  (N quarter: 64 cols)
  const int lrow = l & 15;
  const int lk = l >> 4;       // k-chunk 0..3

  const int sr = t >> 2;
  const int sch = ((t & 3) + (sr >> 1)) & 3;
  const u16* gA = W2 + (size_t)(m0 + sr) * 512 + (sch << 3);
  const u16* gB = xT + (size_t)(n0 + sr) * 512 + (sch << 3);
  const int stg = t << 3;      // u16 offset in 8 KB slab

  const int sk8 = ((lk - (lrow >> 1)) & 3) << 3;
  const int arow = (wm << 6) + lrow;
  const int brow = (wn << 6) + lrow;

  f32x4 acc[4][4] = {};

#define STG(buf_, kt_)                                              \
  async16(&sm.g.A[buf_][stg], gA + (kt_) * 32);                     \
  async16(&sm.g.B[buf_][stg], gB + (kt_) * 32);                     \
  async16(&sm.g.B[buf_][4096 + stg], gB + (kt_) * 32 + 128 * 512)

  STG(0, 0);
  STG(1, 1);
  asm volatile("s_waitcnt vmcnt(3)" ::: "memory");
  asm volatile("s_barrier" ::: "memory");

  int buf = 0, nxt = 2;
  for (int kt = 0; kt < 16; ++kt) {
    const u16* Ab = sm.g.A[buf];
    const u16* Bb = sm.g.B[buf];
    bf16x8 av[4], bv[4];
#pragma unroll
    for (int i = 0; i < 4; ++i)
      av[i] = *(const bf16x8*)(Ab + (arow + i * 16) * 32 + sk8);
#pragma unroll
    for (int j = 0; j < 4; ++j)
      bv[j] = *(const bf16x8*)(Bb + (brow + j * 16) * 32 + sk8);
    if (kt < 14) { STG(nxt, kt + 2); }
    asm volatile("s_waitcnt lgkmcnt(0)" ::: "memory");
    __builtin_amdgcn_sched_barrier(0);
    __builtin_amdgcn_s_setprio(1);
#pragma unroll
    for (int i = 0; i < 4; ++i)
#pragma unroll
      for (int j = 0; j < 4; ++j)
        acc[i][j] = __builtin_amdgcn_mfma_f32_16x16x32_bf16(av[i], bv[j], acc[i][j], 0, 0, 0);
    __builtin_amdgcn_s_setprio(0);
    if (kt <= 13) {
      asm volatile("s_waitcnt vmcnt(3)" ::: "memory");
    } else if (kt == 14) {
      asm volatile("s_waitcnt vmcnt(0)" ::: "memory");
    }
    asm volatile("s_barrier" ::: "memory");
    buf = (buf == 2) ? 0 : buf + 1;
    nxt = (nxt == 2) ? 0 : nxt + 1;
  }
#undef STG

  __syncthreads();  // ring dead; reuse LDS as C tile
  const int crow0 = (wm << 6) + (lk << 2);
  const int ccol0 = (wn << 6) + lrow;
#pragma unroll
  for (int i = 0; i < 4; ++i)
#pragma unroll
    for (int j = 0; j < 4; ++j)
#pragma unroll
      for (int r = 0; r < 4; ++r)
        sm.C[(crow0 + i * 16 + r) * 264 + ccol0 + j * 16] = f2bf(acc[i][j][r]);
  __syncthreads();
  u16* zb = Z + (size_t)m0 * 16384 + n0;
#pragma unroll
  for (int k = 0; k < 8; ++k) {
    int c = (k << 9) | t;
    int row = c >> 5;
    int c8 = (c & 31) << 3;
    *(u16x8*)(zb + (size_t)row * 16384 + c8) = *(const u16x8*)(sm.C + row * 264 + c8);
  }
}

// ---- scatter: polyphase separable FIR + epilogue -----------------------------
// R14 phase-3: thread = (i, jquad): i = t>>4 in [0,32), q = t&15 covers
// j = 4q..4q+3 via H half-pairs (col 2q/2q+1 of half0/half1). float2 H reads
// (uniform 4-deep bank load = LDS floor), float4 noise loads, 2x float4 out
// stores. No serial rolling chain.
__global__ __launch_bounds__(512) void k_scatter(
    const u16* __restrict__ Z, const float* __restrict__ dcoef,
    const float* __restrict__ noise, const float* __restrict__ nstr,
    const float* __restrict__ bias, float* __restrict__ out) {
  __shared__ u16 Zl[9 * 1024];
  __shared__ float Hl[3 * 2048];
  const int o = blockIdx.x;
  const int b = blockIdx.y;
  const int t = threadIdx.x;
  const u16* Zp = Z + (size_t)o * 9 * 16384 + (size_t)b * 1024;
  for (int v = t; v < 1152; v += 512) {
    int kp = v >> 7, off = (v & 127) << 3;
    *(u16x8*)(Zl + kp * 1024 + off) = *(const u16x8*)(Zp + (size_t)kp * 16384 + off);
  }
  __syncthreads();
#pragma unroll
  for (int e = 0; e < 6; ++e) {
    int idx = e * 512 + t;
    int ky = idx >> 10;
    int i = (idx >> 5) & 31;
    int j = idx & 31;
    const u16* P0 = Zl + (ky * 3 + 0) * 1024 + i * 32;
    const u16* P1 = P0 + 1024;
    const u16* P2 = P0 + 2048;
    float Ej = bf2f(P0[j]) + (j >= 1 ? bf2f(P2[j - 1]) : 0.f);
    float Ej1 = (j < 31 ? bf2f(P0[j + 1]) : 0.f) + bf2f(P2[j]);
    float Ojm = j >= 1 ? bf2f(P1[j - 1]) : 0.f;
    float Oj = bf2f(P1[j]);
    float Ojp = j < 31 ? bf2f(P1[j + 1]) : 0.f;
    float* hp = Hl + ky * 2048 + i * 64 + j;
    hp[0] = Ojm + 3.f * Ej + 3.f * Oj + Ej1;
    hp[32] = Ej + 3.f * Oj + 3.f * Ej1 + Ojp;
  }
  __syncthreads();
  const float dc = dcoef[b * 512 + o] * 0.0625f;
  const float ns = nstr[0];
  const float bo = bias[o];
  const int q = t & 15;           // j-quad: cols 4q..4q+3
  const int i = t >> 4;           // 0..31 -> out rows 2i, 2i+1
  const int cb = 2 * q;           // column base within H halves
  // H row reads: A = half0 cols (2q,2q+1), B = half1 cols (32+2q,32+2q+1)
#define LD2(ky_, r_) *(const float2*)(Hl + (ky_) * 2048 + (r_) * 64 + cb)
#define LD2H(ky_, r_) *(const float2*)(Hl + (ky_) * 2048 + (r_) * 64 + 32 + cb)
  const float2 z2 = {0.f, 0.f};
  float2 A0c = LD2(0, i), B0c = LD2H(0, i);
  float2 A1c = LD2(1, i), B1c = LD2H(1, i);
  float2 A2c = LD2(2, i), B2c = LD2H(2, i);
  float2 A0n = (i < 31) ? LD2(0, i + 1) : z2;
  float2 B0n = (i < 31) ? LD2H(0, i + 1) : z2;
  float2 A1n = (i < 31) ? LD2(1, i + 1) : z2;
  float2 B1n = (i < 31) ? LD2H(1, i + 1) : z2;
  float2 A1p = (i > 0) ? LD2(1, i - 1) : z2;
  float2 B1p = (i > 0) ? LD2H(1, i - 1) : z2;
  float2 A2p = (i > 0) ? LD2(2, i - 1) : z2;
  float2 B2p = (i > 0) ? LD2H(2, i - 1) : z2;
#undef LD2
#undef LD2H
  const int m = 2 * i;
  const float* nzb = noise + ((size_t)b << 12) + (size_t)m * 64 + 4 * q;
  const float4 nz0 = *(const float4*)(nzb);
  const float4 nz1 = *(const float4*)(nzb + 64);
  // per-col c: 0 -> .x of A-pairs, 1 -> .x of B-pairs, 2 -> .y A, 3 -> .y B
  float ev[4], od[4];
#define COLS(c_, f_)                                                     \
  ev[c_] = f_(A1p, B1p) + 3.f * (f_(A0c, B0c) + f_(A2p, B2p)) +          \
           3.f * f_(A1c, B1c) + (f_(A0n, B0n) + f_(A2c, B2c));           \
  od[c_] = (f_(A0c, B0c) + f_(A2p, B2p)) + 3.f * f_(A1c, B1c) +          \
           3.f * (f_(A0n, B0n) + f_(A2c, B2c)) + f_(A1n, B1n)
#define FAX(a_, b_) (a_.x)
#define FBX(a_, b_) (b_.x)
#define FAY(a_, b_) (a_.y)
#define FBY(a_, b_) (b_.y)
  COLS(0, FAX);
  COLS(1, FBX);
  COLS(2, FAY);
  COLS(3, FBY);
#undef COLS
#undef FAX
#undef FBX
#undef FAY
#undef FBY
  float4 r0, r1;
  {
    float* e = ev;
    float* d = od;
    const float nzs0[4] = {nz0.x, nz0.y, nz0.z, nz0.w};
    const float nzs1[4] = {nz1.x, nz1.y, nz1.z, nz1.w};
    float o0[4], o1[4];
#pragma unroll
    for (int c = 0; c < 4; ++c) {
      float v0 = e[c] * dc + nzs0[c] * ns + bo;
      v0 = (v0 > 0.f ? v0 : 0.2f * v0) * 1.4142135623730951f;
      o0[c] = fminf(fmaxf(v0, -256.f), 256.f);
      float v1 = d[c] * dc + nzs1[c] * ns + bo;
      v1 = (v1 > 0.f ? v1 : 0.2f * v1) * 1.4142135623730951f;
      o1[c] = fminf(fmaxf(v1, -256.f), 256.f);
    }
    r0 = {o0[0], o0[1], o0[2], o0[3]};
    r1 = {o1[0], o1[1], o1[2], o1[3]};
  }
  float* ob = out + (((size_t)(b * 512 + o)) << 12) + (size_t)m * 64 + 4 * q;
  *(float4*)(ob) = r0;
  *(float4*)(ob + 64) = r1;
}

extern "C" void kernel_launch(void* const* d_in, const int* in_sizes, int n_in,
                              void* d_out, int out_size, void* d_ws, size_t ws_size,
                              hipStream_t stream) {
  const float* x = (const float*)d_in[0];
  const float* wl = (const float*)d_in[1];
  const float* aw = (const float*)d_in[2];
  const float* ab = (const float*)d_in[3];
  const float* cw = (const float*)d_in[4];
  const float* noise = (const float*)d_in[5];
  const float* nstr = (const float*)d_in[6];
  const float* bias = (const float*)d_in[7];
  float* out = (float*)d_out;

  float* style = (float*)d_ws;
  float* dcoef = style + 8192;
  u16* W2 = (u16*)(dcoef + 8192);
  u16* xT = W2 + 4608 * 512;
  u16* Z = xT + (size_t)16384 * 512;

  k_style<<<dim3(8, 16), 256, 0, stream>>>(wl, aw, ab, style);
  k_wprep<<<dim3(512), 256, 0, stream>>>(cw, style, dcoef, W2);
  k_xt<<<dim3(16, 8, 16), 256, 0, stream>>>(x, style, xT);
  k_gemm<<<dim3(64, 36), 512, 0, stream>>>(W2, xT, Z);
  k_scatter<<<dim3(512, 16), 512, 0, stream>>>(Z, dcoef, noise, nstr, bias, out);
}